// Round 1
// baseline (1317.679 us; speedup 1.0000x reference)
//
#include <hip/hip_runtime.h>
#include <stdint.h>

#define N_NODES 100000
#define N_EDGES 1000000
#define HID 128

// ---------------- CSR build ----------------

__global__ void k_count(const int* __restrict__ dst, int* __restrict__ deg) {
  int i = blockIdx.x * 256 + threadIdx.x;
  if (i < N_EDGES) atomicAdd(&deg[dst[i]], 1);
}

// 98 blocks x 256 threads x 4 items = 100352 >= N_NODES
__global__ void k_scan1(const int* __restrict__ deg, int* __restrict__ ex,
                        int* __restrict__ bsum) {
  __shared__ int lds[256];
  int t = threadIdx.x;
  int base = blockIdx.x * 1024 + t * 4;
  int v0 = (base + 0 < N_NODES) ? deg[base + 0] : 0;
  int v1 = (base + 1 < N_NODES) ? deg[base + 1] : 0;
  int v2 = (base + 2 < N_NODES) ? deg[base + 2] : 0;
  int v3 = (base + 3 < N_NODES) ? deg[base + 3] : 0;
  int s = v0 + v1 + v2 + v3;
  lds[t] = s;
  __syncthreads();
  for (int off = 1; off < 256; off <<= 1) {
    int add = (t >= off) ? lds[t - off] : 0;
    __syncthreads();
    lds[t] += add;
    __syncthreads();
  }
  int excl = lds[t] - s;
  if (t == 255) bsum[blockIdx.x] = lds[255];
  if (base + 0 < N_NODES) ex[base + 0] = excl;
  if (base + 1 < N_NODES) ex[base + 1] = excl + v0;
  if (base + 2 < N_NODES) ex[base + 2] = excl + v0 + v1;
  if (base + 3 < N_NODES) ex[base + 3] = excl + v0 + v1 + v2;
}

// single block, 128 threads, exclusive-scan the 98 block sums
__global__ void k_scan2(int* __restrict__ bsum) {
  __shared__ int lds[128];
  int t = threadIdx.x;
  int v = (t < 98) ? bsum[t] : 0;
  lds[t] = v;
  __syncthreads();
  for (int off = 1; off < 128; off <<= 1) {
    int add = (t >= off) ? lds[t - off] : 0;
    __syncthreads();
    lds[t] += add;
    __syncthreads();
  }
  if (t < 98) bsum[t] = lds[t] - v;
}

__global__ void k_scan3(const int* __restrict__ deg, int* __restrict__ row_off,
                        int* __restrict__ cursor, float* __restrict__ dinv,
                        const int* __restrict__ bsum) {
  int i = blockIdx.x * 256 + threadIdx.x;
  if (i < N_NODES) {
    int r = row_off[i] + bsum[i >> 10];
    row_off[i] = r;
    cursor[i] = r;
    int d = deg[i];
    dinv[i] = (d > 0) ? 1.0f / (float)d : 0.0f;
  }
  if (i == 0) row_off[N_NODES] = N_EDGES;
}

__global__ void k_fill(const int* __restrict__ src, const int* __restrict__ dst,
                       int* __restrict__ cursor, int* __restrict__ csr) {
  int i = blockIdx.x * 256 + threadIdx.x;
  if (i < N_EDGES) {
    int d = dst[i];
    int pos = atomicAdd(&cursor[d], 1);
    csr[pos] = src[i];
  }
}

// ---------------- aggregation: nm[n] = mean over neighbors of feat ----------------
// one wave per node; lane handles float2 -> 128 feats
__global__ void k_agg(const float* __restrict__ feat, const int* __restrict__ row_off,
                      const int* __restrict__ csr, const float* __restrict__ dinv,
                      float* __restrict__ nm) {
  int wave = threadIdx.x >> 6;
  int lane = threadIdx.x & 63;
  int node = blockIdx.x * 4 + wave;
  if (node >= N_NODES) return;
  int s0 = row_off[node];
  int s1 = row_off[node + 1];
  float ax = 0.f, ay = 0.f;
  for (int j = s0; j < s1; j++) {
    int s = csr[j];
    float2 v = ((const float2*)(feat + (size_t)s * 128))[lane];
    ax += v.x;
    ay += v.y;
  }
  float di = dinv[node];
  float2 o;
  o.x = ax * di;
  o.y = ay * di;
  ((float2*)(nm + (size_t)node * 128))[lane] = o;
}

// ---------------- fused GEMM: OUT = act(X@WS + NM@WN + B) ----------------
__device__ __forceinline__ float f4get(const float4 v, int i) {
  return i == 0 ? v.x : i == 1 ? v.y : i == 2 ? v.z : v.w;
}

template <int NOUT, bool RELU>
__global__ void k_gemm(const float* __restrict__ X, const float* __restrict__ NM,
                       const float* __restrict__ WS, const float* __restrict__ WN,
                       const float* __restrict__ Bv, float* __restrict__ OUT) {
  constexpr int CG = NOUT / 8;   // colgroups (8 cols each)
  constexpr int NT = 16 * CG;    // threads (16 rowgroups x 4 rows = 64-row tile)
  __shared__ float xs[64 * 132];
  __shared__ float ns[64 * 132];
  const int row0 = blockIdx.x * 64;

  for (int i = threadIdx.x; i < 64 * 32; i += NT) {
    int r = i >> 5, c4 = i & 31;
    int gr = row0 + r;
    if (gr >= N_NODES) gr = N_NODES - 1;
    ((float4*)(xs + r * 132))[c4] = ((const float4*)(X + (size_t)gr * 128))[c4];
    ((float4*)(ns + r * 132))[c4] = ((const float4*)(NM + (size_t)gr * 128))[c4];
  }
  __syncthreads();

  const int cg = threadIdx.x % CG;
  const int rg = threadIdx.x / CG;
  const int c0 = cg * 8;
  const int r0 = rg * 4;

  float acc[4][8];
#pragma unroll
  for (int r = 0; r < 4; r++)
#pragma unroll
    for (int c = 0; c < 8; c++) acc[r][c] = 0.f;

  for (int k = 0; k < 128; k += 4) {
    float4 xv[4], nv[4];
#pragma unroll
    for (int r = 0; r < 4; r++) {
      xv[r] = *(const float4*)(xs + (r0 + r) * 132 + k);
      nv[r] = *(const float4*)(ns + (r0 + r) * 132 + k);
    }
#pragma unroll
    for (int i = 0; i < 4; i++) {
      const float4 w0 = *(const float4*)(WS + (size_t)(k + i) * NOUT + c0);
      const float4 w1 = *(const float4*)(WS + (size_t)(k + i) * NOUT + c0 + 4);
      const float4 u0 = *(const float4*)(WN + (size_t)(k + i) * NOUT + c0);
      const float4 u1 = *(const float4*)(WN + (size_t)(k + i) * NOUT + c0 + 4);
#pragma unroll
      for (int r = 0; r < 4; r++) {
        float xk = f4get(xv[r], i);
        float nk = f4get(nv[r], i);
        acc[r][0] += xk * w0.x; acc[r][1] += xk * w0.y;
        acc[r][2] += xk * w0.z; acc[r][3] += xk * w0.w;
        acc[r][4] += xk * w1.x; acc[r][5] += xk * w1.y;
        acc[r][6] += xk * w1.z; acc[r][7] += xk * w1.w;
        acc[r][0] += nk * u0.x; acc[r][1] += nk * u0.y;
        acc[r][2] += nk * u0.z; acc[r][3] += nk * u0.w;
        acc[r][4] += nk * u1.x; acc[r][5] += nk * u1.y;
        acc[r][6] += nk * u1.z; acc[r][7] += nk * u1.w;
      }
    }
  }

  const float4 bb0 = *(const float4*)(Bv + c0);
  const float4 bb1 = *(const float4*)(Bv + c0 + 4);
#pragma unroll
  for (int r = 0; r < 4; r++) {
    int gr = row0 + r0 + r;
    if (gr < N_NODES) {
      float o[8];
      o[0] = acc[r][0] + bb0.x; o[1] = acc[r][1] + bb0.y;
      o[2] = acc[r][2] + bb0.z; o[3] = acc[r][3] + bb0.w;
      o[4] = acc[r][4] + bb1.x; o[5] = acc[r][5] + bb1.y;
      o[6] = acc[r][6] + bb1.z; o[7] = acc[r][7] + bb1.w;
      if (RELU) {
#pragma unroll
        for (int c = 0; c < 8; c++) o[c] = fmaxf(o[c], 0.f);
      }
      float4 s0 = {o[0], o[1], o[2], o[3]};
      float4 s1 = {o[4], o[5], o[6], o[7]};
      *(float4*)(OUT + (size_t)gr * NOUT + c0) = s0;
      *(float4*)(OUT + (size_t)gr * NOUT + c0 + 4) = s1;
    }
  }
}

// ---------------- launch ----------------

extern "C" void kernel_launch(void* const* d_in, const int* in_sizes, int n_in,
                              void* d_out, int out_size, void* d_ws, size_t ws_size,
                              hipStream_t stream) {
  const float* x   = (const float*)d_in[0];
  const int*   src = (const int*)d_in[1];
  const int*   dst = (const int*)d_in[2];
  const float* ws0 = (const float*)d_in[3];
  const float* wn0 = (const float*)d_in[4];
  const float* b0  = (const float*)d_in[5];
  const float* ws1 = (const float*)d_in[6];
  const float* wn1 = (const float*)d_in[7];
  const float* b1  = (const float*)d_in[8];
  const float* ws2 = (const float*)d_in[9];
  const float* wn2 = (const float*)d_in[10];
  const float* b2  = (const float*)d_in[11];
  float* out = (float*)d_out;

  uint8_t* base = (uint8_t*)d_ws;
  size_t off = 0;
  auto alloc = [&](size_t bytes) -> void* {
    void* p = base + off;
    off = (off + bytes + 255) & ~(size_t)255;
    return p;
  };
  int*   deg     = (int*)alloc((size_t)N_NODES * 4);
  int*   row_off = (int*)alloc((size_t)(N_NODES + 1) * 4);
  int*   cursor  = (int*)alloc((size_t)N_NODES * 4);
  int*   bsum    = (int*)alloc(128 * 4);
  float* dinv    = (float*)alloc((size_t)N_NODES * 4);
  int*   csr     = (int*)alloc((size_t)N_EDGES * 4);
  float* nm      = (float*)alloc((size_t)N_NODES * 128 * 4);
  float* h1      = (float*)alloc((size_t)N_NODES * 128 * 4);
  float* h2      = (float*)alloc((size_t)N_NODES * 128 * 4);

  hipMemsetAsync(deg, 0, (size_t)N_NODES * 4, stream);
  k_count<<<(N_EDGES + 255) / 256, 256, 0, stream>>>(dst, deg);
  k_scan1<<<98, 256, 0, stream>>>(deg, row_off, bsum);
  k_scan2<<<1, 128, 0, stream>>>(bsum);
  k_scan3<<<(N_NODES + 255) / 256, 256, 0, stream>>>(deg, row_off, cursor, dinv, bsum);
  k_fill<<<(N_EDGES + 255) / 256, 256, 0, stream>>>(src, dst, cursor, csr);

  // layer 0
  k_agg<<<25000, 256, 0, stream>>>(x, row_off, csr, dinv, nm);
  k_gemm<128, true><<<1563, 256, 0, stream>>>(x, nm, ws0, wn0, b0, h1);
  // layer 1
  k_agg<<<25000, 256, 0, stream>>>(h1, row_off, csr, dinv, nm);
  k_gemm<128, true><<<1563, 256, 0, stream>>>(h1, nm, ws1, wn1, b1, h2);
  // layer 2
  k_agg<<<25000, 256, 0, stream>>>(h2, row_off, csr, dinv, nm);
  k_gemm<64, false><<<1563, 128, 0, stream>>>(h2, nm, ws2, wn2, b2, out);
}

// Round 2
// 516.563 us; speedup vs baseline: 2.5509x; 2.5509x over previous
//
#include <hip/hip_runtime.h>
#include <stdint.h>

#define N_NODES 100000
#define N_EDGES 1000000

typedef __attribute__((ext_vector_type(8))) short bf16x8;
typedef __attribute__((ext_vector_type(4))) float f32x4;

__device__ __forceinline__ unsigned short f2b(float f) {
  unsigned int u = __float_as_uint(f);
  unsigned int r = (u + 0x7fffu + ((u >> 16) & 1u)) >> 16;
  return (unsigned short)r;
}
__device__ __forceinline__ float b2f(unsigned int lo16) {
  return __uint_as_float(lo16 << 16);
}

// ---------------- CSR build ----------------

__global__ void k_count(const int* __restrict__ dst, int* __restrict__ deg) {
  int i = blockIdx.x * 256 + threadIdx.x;
  if (i < N_EDGES) atomicAdd(&deg[dst[i]], 1);
}

__global__ void k_scan1(const int* __restrict__ deg, int* __restrict__ ex,
                        int* __restrict__ bsum) {
  __shared__ int lds[256];
  int t = threadIdx.x;
  int base = blockIdx.x * 1024 + t * 4;
  int v0 = (base + 0 < N_NODES) ? deg[base + 0] : 0;
  int v1 = (base + 1 < N_NODES) ? deg[base + 1] : 0;
  int v2 = (base + 2 < N_NODES) ? deg[base + 2] : 0;
  int v3 = (base + 3 < N_NODES) ? deg[base + 3] : 0;
  int s = v0 + v1 + v2 + v3;
  lds[t] = s;
  __syncthreads();
  for (int off = 1; off < 256; off <<= 1) {
    int add = (t >= off) ? lds[t - off] : 0;
    __syncthreads();
    lds[t] += add;
    __syncthreads();
  }
  int excl = lds[t] - s;
  if (t == 255) bsum[blockIdx.x] = lds[255];
  if (base + 0 < N_NODES) ex[base + 0] = excl;
  if (base + 1 < N_NODES) ex[base + 1] = excl + v0;
  if (base + 2 < N_NODES) ex[base + 2] = excl + v0 + v1;
  if (base + 3 < N_NODES) ex[base + 3] = excl + v0 + v1 + v2;
}

__global__ void k_scan2(int* __restrict__ bsum) {
  __shared__ int lds[128];
  int t = threadIdx.x;
  int v = (t < 98) ? bsum[t] : 0;
  lds[t] = v;
  __syncthreads();
  for (int off = 1; off < 128; off <<= 1) {
    int add = (t >= off) ? lds[t - off] : 0;
    __syncthreads();
    lds[t] += add;
    __syncthreads();
  }
  if (t < 98) bsum[t] = lds[t] - v;
}

__global__ void k_scan3(const int* __restrict__ deg, int* __restrict__ row_off,
                        int* __restrict__ cursor, float* __restrict__ dinv,
                        const int* __restrict__ bsum) {
  int i = blockIdx.x * 256 + threadIdx.x;
  if (i < N_NODES) {
    int r = row_off[i] + bsum[i >> 10];
    row_off[i] = r;
    cursor[i] = r;
    int d = deg[i];
    dinv[i] = (d > 0) ? 1.0f / (float)d : 0.0f;
  }
  if (i == 0) row_off[N_NODES] = N_EDGES;
}

__global__ void k_fill(const int* __restrict__ src, const int* __restrict__ dst,
                       int* __restrict__ cursor, int* __restrict__ csr) {
  int i = blockIdx.x * 256 + threadIdx.x;
  if (i < N_EDGES) {
    int d = dst[i];
    int pos = atomicAdd(&cursor[d], 1);
    csr[pos] = src[i];
  }
}

// ---------------- fp32 -> bf16 cast (x) ----------------
__global__ void k_cast(const float* __restrict__ x, unsigned short* __restrict__ xb) {
  int i = blockIdx.x * 256 + threadIdx.x;
  if (i >= N_NODES * 16) return;
  float4 a = ((const float4*)x)[2 * i];
  float4 b = ((const float4*)x)[2 * i + 1];
  unsigned short r[8] = {f2b(a.x), f2b(a.y), f2b(a.z), f2b(a.w),
                         f2b(b.x), f2b(b.y), f2b(b.z), f2b(b.w)};
  *(uint4*)(xb + (size_t)i * 8) = *(uint4*)r;
}

// ---------------- weight prep: bf16, transposed + K-concat: wt[n][0:128]=WS^T, [128:256]=WN^T
__global__ void k_wprep(const float* __restrict__ WS, const float* __restrict__ WN,
                        int nout, unsigned short* __restrict__ wt) {
  int t = blockIdx.x * 256 + threadIdx.x;
  if (t >= nout * 128) return;
  int n = t >> 7, k = t & 127;
  wt[n * 256 + k] = f2b(WS[(size_t)k * nout + n]);
  wt[n * 256 + 128 + k] = f2b(WN[(size_t)k * nout + n]);
}

// ---------------- aggregation (bf16 feat): one wave per node ----------------
__global__ void k_agg(const unsigned short* __restrict__ feat,
                      const int* __restrict__ row_off, const int* __restrict__ csr,
                      const float* __restrict__ dinv, unsigned short* __restrict__ nm) {
  int wv = threadIdx.x >> 6, lane = threadIdx.x & 63;
  int node = blockIdx.x * 4 + wv;
  if (node >= N_NODES) return;
  int s0 = row_off[node];
  int s1 = row_off[node + 1];
  float ax = 0.f, ay = 0.f;
  for (int j = s0; j < s1; j++) {
    int s = csr[j];
    unsigned int v = ((const unsigned int*)(feat + (size_t)s * 128))[lane];
    ax += b2f(v & 0xffffu);
    ay += __uint_as_float(v & 0xffff0000u);
  }
  float di = dinv[node];
  unsigned int o = ((unsigned int)f2b(ay * di) << 16) | (unsigned int)f2b(ax * di);
  ((unsigned int*)(nm + (size_t)node * 128))[lane] = o;
}

// ---------------- MFMA GEMM: OUT = act([A0|A1] @ WT^T + B) ----------------
// A0,A1: [N_NODES][128] bf16. WT: [NOUT][256] bf16 (transposed+concat).
// 64-row tile per block, 4 waves split NOUT columns (NOUT/4 each).
template <int NOUT, bool RELU, bool OUT_BF16>
__global__ __launch_bounds__(256, 4) void k_mm(
    const unsigned short* __restrict__ A0, const unsigned short* __restrict__ A1,
    const unsigned short* __restrict__ WT, const float* __restrict__ Bv,
    void* __restrict__ OUT) {
  constexpr int NFC = NOUT / 64;  // col-frags per wave
  __shared__ __align__(16) unsigned short sm[16896];  // 33792 B
  const int row0 = blockIdx.x * 64;
  const int tid = threadIdx.x;

  // stage A tile [64][264]: cols 0..127 from A0, 128..255 from A1 (pad 8)
  for (int i = tid; i < 1024; i += 256) {
    int r = i >> 4, c = i & 15;
    int gr = row0 + r;
    if (gr >= N_NODES) gr = N_NODES - 1;
    *(uint4*)(sm + r * 264 + c * 8) = ((const uint4*)(A0 + (size_t)gr * 128))[c];
    *(uint4*)(sm + r * 264 + 128 + c * 8) = ((const uint4*)(A1 + (size_t)gr * 128))[c];
  }

  const int lane = tid & 63;
  const int w = tid >> 6;
  const int r16 = lane & 15;
  const int kg = lane >> 4;
  const int wc0 = w * (NOUT / 4);

  f32x4 acc[4][NFC];
#pragma unroll
  for (int rf = 0; rf < 4; rf++)
#pragma unroll
    for (int cf = 0; cf < NFC; cf++) acc[rf][cf] = (f32x4){0.f, 0.f, 0.f, 0.f};

  __syncthreads();

  const unsigned short* wtb = WT + (size_t)(wc0 + r16) * 256 + kg * 8;
  const unsigned short* asb = sm + r16 * 264 + kg * 8;

  for (int ks = 0; ks < 8; ks++) {
    bf16x8 a[4];
#pragma unroll
    for (int rf = 0; rf < 4; rf++)
      a[rf] = *(const bf16x8*)(asb + rf * 16 * 264 + ks * 32);
#pragma unroll
    for (int cf = 0; cf < NFC; cf++) {
      bf16x8 b = *(const bf16x8*)(wtb + cf * 16 * 256 + ks * 32);
#pragma unroll
      for (int rf = 0; rf < 4; rf++)
        acc[rf][cf] = __builtin_amdgcn_mfma_f32_16x16x32_bf16(a[rf], b, acc[rf][cf], 0, 0, 0);
    }
  }

  __syncthreads();  // done reading A tile; reuse sm for output staging

  if (OUT_BF16) {
    constexpr int LSO = NOUT + 8;
    unsigned short* so = sm;
#pragma unroll
    for (int rf = 0; rf < 4; rf++)
#pragma unroll
      for (int cf = 0; cf < NFC; cf++) {
        int col = wc0 + cf * 16 + r16;
        float bias = Bv[col];
#pragma unroll
        for (int r = 0; r < 4; r++) {
          int row = rf * 16 + kg * 4 + r;
          float v = acc[rf][cf][r] + bias;
          if (RELU) v = fmaxf(v, 0.f);
          so[row * LSO + col] = f2b(v);
        }
      }
    __syncthreads();
    unsigned short* O = (unsigned short*)OUT;
    for (int i = tid; i < 64 * (NOUT / 8); i += 256) {
      int r = i / (NOUT / 8), c = i % (NOUT / 8);
      int gr = row0 + r;
      if (gr < N_NODES)
        *(uint4*)(O + (size_t)gr * NOUT + c * 8) = *(const uint4*)(so + r * LSO + c * 8);
    }
  } else {
    constexpr int LSO = NOUT + 4;
    float* so = (float*)sm;
#pragma unroll
    for (int rf = 0; rf < 4; rf++)
#pragma unroll
      for (int cf = 0; cf < NFC; cf++) {
        int col = wc0 + cf * 16 + r16;
        float bias = Bv[col];
#pragma unroll
        for (int r = 0; r < 4; r++) {
          int row = rf * 16 + kg * 4 + r;
          float v = acc[rf][cf][r] + bias;
          if (RELU) v = fmaxf(v, 0.f);
          so[row * LSO + col] = v;
        }
      }
    __syncthreads();
    float* O = (float*)OUT;
    for (int i = tid; i < 64 * (NOUT / 4); i += 256) {
      int r = i / (NOUT / 4), c = i % (NOUT / 4);
      int gr = row0 + r;
      if (gr < N_NODES)
        *(float4*)(O + (size_t)gr * NOUT + c * 4) = *(const float4*)(so + r * LSO + c * 4);
    }
  }
}

// ---------------- launch ----------------

extern "C" void kernel_launch(void* const* d_in, const int* in_sizes, int n_in,
                              void* d_out, int out_size, void* d_ws, size_t ws_size,
                              hipStream_t stream) {
  const float* x   = (const float*)d_in[0];
  const int*   src = (const int*)d_in[1];
  const int*   dst = (const int*)d_in[2];
  const float* ws0 = (const float*)d_in[3];
  const float* wn0 = (const float*)d_in[4];
  const float* b0  = (const float*)d_in[5];
  const float* ws1 = (const float*)d_in[6];
  const float* wn1 = (const float*)d_in[7];
  const float* b1  = (const float*)d_in[8];
  const float* ws2 = (const float*)d_in[9];
  const float* wn2 = (const float*)d_in[10];
  const float* b2  = (const float*)d_in[11];
  float* out = (float*)d_out;

  uint8_t* base = (uint8_t*)d_ws;
  size_t off = 0;
  auto alloc = [&](size_t bytes) -> void* {
    void* p = base + off;
    off = (off + bytes + 255) & ~(size_t)255;
    return p;
  };
  int*   deg     = (int*)alloc((size_t)N_NODES * 4);
  int*   row_off = (int*)alloc((size_t)(N_NODES + 1) * 4);
  int*   cursor  = (int*)alloc((size_t)N_NODES * 4);
  int*   bsum    = (int*)alloc(128 * 4);
  float* dinv    = (float*)alloc((size_t)N_NODES * 4);
  int*   csr     = (int*)alloc((size_t)N_EDGES * 4);
  unsigned short* xb  = (unsigned short*)alloc((size_t)N_NODES * 128 * 2);
  unsigned short* nmb = (unsigned short*)alloc((size_t)N_NODES * 128 * 2);
  unsigned short* h1b = (unsigned short*)alloc((size_t)N_NODES * 128 * 2);
  unsigned short* h2b = (unsigned short*)alloc((size_t)N_NODES * 128 * 2);
  unsigned short* wt0 = (unsigned short*)alloc(128 * 256 * 2);
  unsigned short* wt1 = (unsigned short*)alloc(128 * 256 * 2);
  unsigned short* wt2 = (unsigned short*)alloc(64 * 256 * 2);

  hipMemsetAsync(deg, 0, (size_t)N_NODES * 4, stream);
  k_count<<<(N_EDGES + 255) / 256, 256, 0, stream>>>(dst, deg);
  k_scan1<<<98, 256, 0, stream>>>(deg, row_off, bsum);
  k_scan2<<<1, 128, 0, stream>>>(bsum);
  k_scan3<<<(N_NODES + 255) / 256, 256, 0, stream>>>(deg, row_off, cursor, dinv, bsum);
  k_fill<<<(N_EDGES + 255) / 256, 256, 0, stream>>>(src, dst, cursor, csr);

  k_cast<<<(N_NODES * 16 + 255) / 256, 256, 0, stream>>>(x, xb);
  k_wprep<<<64, 256, 0, stream>>>(ws0, wn0, 128, wt0);
  k_wprep<<<64, 256, 0, stream>>>(ws1, wn1, 128, wt1);
  k_wprep<<<32, 256, 0, stream>>>(ws2, wn2, 64, wt2);

  const int GMM = (N_NODES + 63) / 64;  // 1563

  // layer 0
  k_agg<<<25000, 256, 0, stream>>>(xb, row_off, csr, dinv, nmb);
  k_mm<128, true, true><<<GMM, 256, 0, stream>>>(xb, nmb, wt0, b0, h1b);
  // layer 1
  k_agg<<<25000, 256, 0, stream>>>(h1b, row_off, csr, dinv, nmb);
  k_mm<128, true, true><<<GMM, 256, 0, stream>>>(h1b, nmb, wt1, b1, h2b);
  // layer 2
  k_agg<<<25000, 256, 0, stream>>>(h2b, row_off, csr, dinv, nmb);
  k_mm<64, false, false><<<GMM, 256, 0, stream>>>(h2b, nmb, wt2, b2, out);
}

// Round 3
// 366.693 us; speedup vs baseline: 3.5934x; 1.4087x over previous
//
#include <hip/hip_runtime.h>
#include <stdint.h>

#define N_NODES 100000
#define N_EDGES 1000000

typedef __attribute__((ext_vector_type(8))) short bf16x8;
typedef __attribute__((ext_vector_type(4))) float f32x4;

__device__ __forceinline__ unsigned short f2b(float f) {
  unsigned int u = __float_as_uint(f);
  unsigned int r = (u + 0x7fffu + ((u >> 16) & 1u)) >> 16;
  return (unsigned short)r;
}
__device__ __forceinline__ float b2f(unsigned int lo16) {
  return __uint_as_float(lo16 << 16);
}

// ---------------- CSR build ----------------

__global__ void k_count(const int* __restrict__ dst, int* __restrict__ deg) {
  int i = blockIdx.x * 256 + threadIdx.x;
  if (i < N_EDGES) atomicAdd(&deg[dst[i]], 1);
}

__global__ void k_scan1(const int* __restrict__ deg, int* __restrict__ ex,
                        int* __restrict__ bsum) {
  __shared__ int lds[256];
  int t = threadIdx.x;
  int base = blockIdx.x * 1024 + t * 4;
  int v0 = (base + 0 < N_NODES) ? deg[base + 0] : 0;
  int v1 = (base + 1 < N_NODES) ? deg[base + 1] : 0;
  int v2 = (base + 2 < N_NODES) ? deg[base + 2] : 0;
  int v3 = (base + 3 < N_NODES) ? deg[base + 3] : 0;
  int s = v0 + v1 + v2 + v3;
  lds[t] = s;
  __syncthreads();
  for (int off = 1; off < 256; off <<= 1) {
    int add = (t >= off) ? lds[t - off] : 0;
    __syncthreads();
    lds[t] += add;
    __syncthreads();
  }
  int excl = lds[t] - s;
  if (t == 255) bsum[blockIdx.x] = lds[255];
  if (base + 0 < N_NODES) ex[base + 0] = excl;
  if (base + 1 < N_NODES) ex[base + 1] = excl + v0;
  if (base + 2 < N_NODES) ex[base + 2] = excl + v0 + v1;
  if (base + 3 < N_NODES) ex[base + 3] = excl + v0 + v1 + v2;
}

__global__ void k_scan2(int* __restrict__ bsum) {
  __shared__ int lds[128];
  int t = threadIdx.x;
  int v = (t < 98) ? bsum[t] : 0;
  lds[t] = v;
  __syncthreads();
  for (int off = 1; off < 128; off <<= 1) {
    int add = (t >= off) ? lds[t - off] : 0;
    __syncthreads();
    lds[t] += add;
    __syncthreads();
  }
  if (t < 98) bsum[t] = lds[t] - v;
}

__global__ void k_scan3(const int* __restrict__ deg, int* __restrict__ row_off,
                        int* __restrict__ cursor, float* __restrict__ dinv,
                        const int* __restrict__ bsum) {
  int i = blockIdx.x * 256 + threadIdx.x;
  if (i < N_NODES) {
    int r = row_off[i] + bsum[i >> 10];
    row_off[i] = r;
    cursor[i] = r;
    int d = deg[i];
    dinv[i] = (d > 0) ? 1.0f / (float)d : 0.0f;
  }
  if (i == 0) row_off[N_NODES] = N_EDGES;
}

__global__ void k_fill(const int* __restrict__ src, const int* __restrict__ dst,
                       int* __restrict__ cursor, int* __restrict__ csr) {
  int i = blockIdx.x * 256 + threadIdx.x;
  if (i < N_EDGES) {
    int d = dst[i];
    int pos = atomicAdd(&cursor[d], 1);
    csr[pos] = src[i];
  }
}

// ---------------- fp32 -> bf16 cast (x) ----------------
__global__ void k_cast(const float* __restrict__ x, unsigned short* __restrict__ xb) {
  int i = blockIdx.x * 256 + threadIdx.x;
  if (i >= N_NODES * 16) return;
  float4 a = ((const float4*)x)[2 * i];
  float4 b = ((const float4*)x)[2 * i + 1];
  unsigned short r[8] = {f2b(a.x), f2b(a.y), f2b(a.z), f2b(a.w),
                         f2b(b.x), f2b(b.y), f2b(b.z), f2b(b.w)};
  *(uint4*)(xb + (size_t)i * 8) = *(uint4*)r;
}

// ---------------- weight prep: bf16, transposed + K-concat ----------------
__global__ void k_wprep(const float* __restrict__ WS, const float* __restrict__ WN,
                        int nout, unsigned short* __restrict__ wt) {
  int t = blockIdx.x * 256 + threadIdx.x;
  if (t >= nout * 128) return;
  int n = t >> 7, k = t & 127;
  wt[n * 256 + k] = f2b(WS[(size_t)k * nout + n]);
  wt[n * 256 + 128 + k] = f2b(WN[(size_t)k * nout + n]);
}

// ---------------- aggregation: one wave per node, 4-deep MLP pipeline ----------------
__global__ void k_agg(const unsigned short* __restrict__ feat,
                      const int* __restrict__ row_off, const int* __restrict__ csr,
                      const float* __restrict__ dinv, unsigned short* __restrict__ nm) {
  int wv = threadIdx.x >> 6, lane = threadIdx.x & 63;
  int node = blockIdx.x * 4 + wv;
  if (node >= N_NODES) return;
  const unsigned int* f32p = (const unsigned int*)feat;
  int s0 = row_off[node];
  int s1 = row_off[node + 1];
  float ax0 = 0.f, ay0 = 0.f, ax1 = 0.f, ay1 = 0.f;
  float ax2 = 0.f, ay2 = 0.f, ax3 = 0.f, ay3 = 0.f;
  int j = s0;
  int nleft = s1 - s0;
  if (nleft >= 4) {
    int c0 = csr[j], c1 = csr[j + 1], c2 = csr[j + 2], c3 = csr[j + 3];
    j += 4; nleft -= 4;
    while (nleft >= 4) {
      int d0 = csr[j], d1 = csr[j + 1], d2 = csr[j + 2], d3 = csr[j + 3];
      j += 4; nleft -= 4;
      unsigned int v0 = f32p[(size_t)c0 * 64 + lane];
      unsigned int v1 = f32p[(size_t)c1 * 64 + lane];
      unsigned int v2 = f32p[(size_t)c2 * 64 + lane];
      unsigned int v3 = f32p[(size_t)c3 * 64 + lane];
      ax0 += b2f(v0 & 0xffffu); ay0 += __uint_as_float(v0 & 0xffff0000u);
      ax1 += b2f(v1 & 0xffffu); ay1 += __uint_as_float(v1 & 0xffff0000u);
      ax2 += b2f(v2 & 0xffffu); ay2 += __uint_as_float(v2 & 0xffff0000u);
      ax3 += b2f(v3 & 0xffffu); ay3 += __uint_as_float(v3 & 0xffff0000u);
      c0 = d0; c1 = d1; c2 = d2; c3 = d3;
    }
    unsigned int v0 = f32p[(size_t)c0 * 64 + lane];
    unsigned int v1 = f32p[(size_t)c1 * 64 + lane];
    unsigned int v2 = f32p[(size_t)c2 * 64 + lane];
    unsigned int v3 = f32p[(size_t)c3 * 64 + lane];
    ax0 += b2f(v0 & 0xffffu); ay0 += __uint_as_float(v0 & 0xffff0000u);
    ax1 += b2f(v1 & 0xffffu); ay1 += __uint_as_float(v1 & 0xffff0000u);
    ax2 += b2f(v2 & 0xffffu); ay2 += __uint_as_float(v2 & 0xffff0000u);
    ax3 += b2f(v3 & 0xffffu); ay3 += __uint_as_float(v3 & 0xffff0000u);
  }
  for (; nleft > 0; nleft--, j++) {
    unsigned int v = f32p[(size_t)csr[j] * 64 + lane];
    ax0 += b2f(v & 0xffffu); ay0 += __uint_as_float(v & 0xffff0000u);
  }
  float ax = (ax0 + ax1) + (ax2 + ax3);
  float ay = (ay0 + ay1) + (ay2 + ay3);
  float di = dinv[node];
  unsigned int o = ((unsigned int)f2b(ay * di) << 16) | (unsigned int)f2b(ax * di);
  ((unsigned int*)(nm + (size_t)node * 128))[lane] = o;
}

// ---------------- MFMA GEMM: OUT = act([A0|A1] @ WT^T + B) ----------------
template <int NOUT, bool RELU, bool OUT_BF16>
__global__ __launch_bounds__(256, 4) void k_mm(
    const unsigned short* __restrict__ A0, const unsigned short* __restrict__ A1,
    const unsigned short* __restrict__ WT, const float* __restrict__ Bv,
    void* __restrict__ OUT) {
  constexpr int NFC = NOUT / 64;  // col-frags per wave
  __shared__ __align__(16) unsigned short sm[16896];  // 33792 B
  const int row0 = blockIdx.x * 64;
  const int tid = threadIdx.x;

  for (int i = tid; i < 1024; i += 256) {
    int r = i >> 4, c = i & 15;
    int gr = row0 + r;
    if (gr >= N_NODES) gr = N_NODES - 1;
    *(uint4*)(sm + r * 264 + c * 8) = ((const uint4*)(A0 + (size_t)gr * 128))[c];
    *(uint4*)(sm + r * 264 + 128 + c * 8) = ((const uint4*)(A1 + (size_t)gr * 128))[c];
  }

  const int lane = tid & 63;
  const int w = tid >> 6;
  const int r16 = lane & 15;
  const int kg = lane >> 4;
  const int wc0 = w * (NOUT / 4);

  f32x4 acc[4][NFC];
#pragma unroll
  for (int rf = 0; rf < 4; rf++)
#pragma unroll
    for (int cf = 0; cf < NFC; cf++) acc[rf][cf] = (f32x4){0.f, 0.f, 0.f, 0.f};

  __syncthreads();

  const unsigned short* wtb = WT + (size_t)(wc0 + r16) * 256 + kg * 8;
  const unsigned short* asb = sm + r16 * 264 + kg * 8;

  for (int ks = 0; ks < 8; ks++) {
    bf16x8 a[4];
#pragma unroll
    for (int rf = 0; rf < 4; rf++)
      a[rf] = *(const bf16x8*)(asb + rf * 16 * 264 + ks * 32);
#pragma unroll
    for (int cf = 0; cf < NFC; cf++) {
      bf16x8 b = *(const bf16x8*)(wtb + cf * 16 * 256 + ks * 32);
#pragma unroll
      for (int rf = 0; rf < 4; rf++)
        acc[rf][cf] = __builtin_amdgcn_mfma_f32_16x16x32_bf16(a[rf], b, acc[rf][cf], 0, 0, 0);
    }
  }

  __syncthreads();  // reuse sm for output staging

  if (OUT_BF16) {
    constexpr int LSO = NOUT + 8;
    unsigned short* so = sm;
#pragma unroll
    for (int rf = 0; rf < 4; rf++)
#pragma unroll
      for (int cf = 0; cf < NFC; cf++) {
        int col = wc0 + cf * 16 + r16;
        float bias = Bv[col];
#pragma unroll
        for (int r = 0; r < 4; r++) {
          int row = rf * 16 + kg * 4 + r;
          float v = acc[rf][cf][r] + bias;
          if (RELU) v = fmaxf(v, 0.f);
          so[row * LSO + col] = f2b(v);
        }
      }
    __syncthreads();
    unsigned short* O = (unsigned short*)OUT;
    for (int i = tid; i < 64 * (NOUT / 8); i += 256) {
      int r = i / (NOUT / 8), c = i % (NOUT / 8);
      int gr = row0 + r;
      if (gr < N_NODES)
        *(uint4*)(O + (size_t)gr * NOUT + c * 8) = *(const uint4*)(so + r * LSO + c * 8);
    }
  } else {
    constexpr int LSO = NOUT + 4;
    float* so = (float*)sm;
#pragma unroll
    for (int rf = 0; rf < 4; rf++)
#pragma unroll
      for (int cf = 0; cf < NFC; cf++) {
        int col = wc0 + cf * 16 + r16;
        float bias = Bv[col];
#pragma unroll
        for (int r = 0; r < 4; r++) {
          int row = rf * 16 + kg * 4 + r;
          float v = acc[rf][cf][r] + bias;
          if (RELU) v = fmaxf(v, 0.f);
          so[row * LSO + col] = v;
        }
      }
    __syncthreads();
    float* O = (float*)OUT;
    for (int i = tid; i < 64 * (NOUT / 4); i += 256) {
      int r = i / (NOUT / 4), c = i % (NOUT / 4);
      int gr = row0 + r;
      if (gr < N_NODES)
        *(float4*)(O + (size_t)gr * NOUT + c * 4) = *(const float4*)(so + r * LSO + c * 4);
    }
  }
}

// ---------------- launch ----------------

extern "C" void kernel_launch(void* const* d_in, const int* in_sizes, int n_in,
                              void* d_out, int out_size, void* d_ws, size_t ws_size,
                              hipStream_t stream) {
  const float* x   = (const float*)d_in[0];
  const int*   src = (const int*)d_in[1];
  const int*   dst = (const int*)d_in[2];
  const float* ws0 = (const float*)d_in[3];
  const float* wn0 = (const float*)d_in[4];
  const float* b0  = (const float*)d_in[5];
  const float* ws1 = (const float*)d_in[6];
  const float* wn1 = (const float*)d_in[7];
  const float* b1  = (const float*)d_in[8];
  const float* ws2 = (const float*)d_in[9];
  const float* wn2 = (const float*)d_in[10];
  const float* b2  = (const float*)d_in[11];
  float* out = (float*)d_out;

  uint8_t* base = (uint8_t*)d_ws;
  size_t off = 0;
  auto alloc = [&](size_t bytes) -> void* {
    void* p = base + off;
    off = (off + bytes + 255) & ~(size_t)255;
    return p;
  };
  int*   deg     = (int*)alloc((size_t)N_NODES * 4);
  int*   row_off = (int*)alloc((size_t)(N_NODES + 1) * 4);
  int*   cursor  = (int*)alloc((size_t)N_NODES * 4);
  int*   bsum    = (int*)alloc(128 * 4);
  float* dinv    = (float*)alloc((size_t)N_NODES * 4);
  int*   csr     = (int*)alloc((size_t)N_EDGES * 4);
  unsigned short* xb  = (unsigned short*)alloc((size_t)N_NODES * 128 * 2);
  unsigned short* nmb = (unsigned short*)alloc((size_t)N_NODES * 128 * 2);
  unsigned short* h1b = (unsigned short*)alloc((size_t)N_NODES * 128 * 2);
  unsigned short* h2b = (unsigned short*)alloc((size_t)N_NODES * 128 * 2);
  unsigned short* wt0 = (unsigned short*)alloc(128 * 256 * 2);
  unsigned short* wt1 = (unsigned short*)alloc(128 * 256 * 2);
  unsigned short* wt2 = (unsigned short*)alloc(64 * 256 * 2);

  hipMemsetAsync(deg, 0, (size_t)N_NODES * 4, stream);
  k_count<<<(N_EDGES + 255) / 256, 256, 0, stream>>>(dst, deg);
  k_scan1<<<98, 256, 0, stream>>>(deg, row_off, bsum);
  k_scan2<<<1, 128, 0, stream>>>(bsum);
  k_scan3<<<(N_NODES + 255) / 256, 256, 0, stream>>>(deg, row_off, cursor, dinv, bsum);
  k_fill<<<(N_EDGES + 255) / 256, 256, 0, stream>>>(src, dst, cursor, csr);

  k_cast<<<(N_NODES * 16 + 255) / 256, 256, 0, stream>>>(x, xb);
  k_wprep<<<64, 256, 0, stream>>>(ws0, wn0, 128, wt0);
  k_wprep<<<64, 256, 0, stream>>>(ws1, wn1, 128, wt1);
  k_wprep<<<32, 256, 0, stream>>>(ws2, wn2, 64, wt2);

  const int GMM = (N_NODES + 63) / 64;  // 1563

  // layer 0
  k_agg<<<25000, 256, 0, stream>>>(xb, row_off, csr, dinv, nmb);
  k_mm<128, true, true><<<GMM, 256, 0, stream>>>(xb, nmb, wt0, b0, h1b);
  // layer 1
  k_agg<<<25000, 256, 0, stream>>>(h1b, row_off, csr, dinv, nmb);
  k_mm<128, true, true><<<GMM, 256, 0, stream>>>(h1b, nmb, wt1, b1, h2b);
  // layer 2
  k_agg<<<25000, 256, 0, stream>>>(h2b, row_off, csr, dinv, nmb);
  k_mm<64, false, false><<<GMM, 256, 0, stream>>>(h2b, nmb, wt2, b2, out);
}

// Round 4
// 330.985 us; speedup vs baseline: 3.9811x; 1.1079x over previous
//
#include <hip/hip_runtime.h>
#include <stdint.h>

#define N_NODES 100000
#define N_EDGES 1000000
#define NB 782  // ceil(N_NODES/128) buckets of 128 nodes

typedef __attribute__((ext_vector_type(8))) short bf16x8;
typedef __attribute__((ext_vector_type(4))) float f32x4;

__device__ __forceinline__ unsigned short f2b(float f) {
  unsigned int u = __float_as_uint(f);
  unsigned int r = (u + 0x7fffu + ((u >> 16) & 1u)) >> 16;
  return (unsigned short)r;
}
__device__ __forceinline__ float b2f(unsigned int lo16) {
  return __uint_as_float(lo16 << 16);
}

// ---------------- bucketed CSR build ----------------

__global__ void k_hist(const int* __restrict__ dst, int* __restrict__ bcount) {
  __shared__ int h[NB];
  int t = threadIdx.x;
  for (int i = t; i < NB; i += 256) h[i] = 0;
  __syncthreads();
  int base = blockIdx.x * 4096;
#pragma unroll
  for (int k = 0; k < 16; k++) {
    int i = base + t + k * 256;
    if (i < N_EDGES) atomicAdd(&h[dst[i] >> 7], 1);
  }
  __syncthreads();
  for (int i = t; i < NB; i += 256)
    if (h[i]) atomicAdd(&bcount[i], h[i]);
}

__global__ __launch_bounds__(1024) void k_bscan(const int* __restrict__ bcount,
                                                int* __restrict__ boff,
                                                int* __restrict__ bcursor) {
  __shared__ int sc[1024];
  int t = threadIdx.x;
  int v = (t < NB) ? bcount[t] : 0;
  sc[t] = v;
  __syncthreads();
  for (int off = 1; off < 1024; off <<= 1) {
    int a = (t >= off) ? sc[t - off] : 0;
    __syncthreads();
    sc[t] += a;
    __syncthreads();
  }
  if (t < NB) {
    boff[t + 1] = sc[t];
    bcursor[t] = sc[t] - v;
  }
  if (t == 0) boff[0] = 0;
}

#define EPB 16384  // edges per scatter block
__global__ void k_scatter(const int* __restrict__ src, const int* __restrict__ dst,
                          int* __restrict__ bcursor, unsigned int* __restrict__ stage) {
  __shared__ int h[NB];
  __shared__ int cur[NB];
  int t = threadIdx.x;
  for (int i = t; i < NB; i += 256) h[i] = 0;
  __syncthreads();
  int base = blockIdx.x * EPB;
#pragma unroll 4
  for (int k = 0; k < EPB / 256; k++) {
    int i = base + t + k * 256;
    if (i < N_EDGES) atomicAdd(&h[dst[i] >> 7], 1);
  }
  __syncthreads();
  for (int i = t; i < NB; i += 256) {
    int c = h[i];
    cur[i] = c ? atomicAdd(&bcursor[i], c) : 0;
  }
  __syncthreads();
#pragma unroll 4
  for (int k = 0; k < EPB / 256; k++) {
    int i = base + t + k * 256;
    if (i < N_EDGES) {
      int d = dst[i];
      int b = d >> 7;
      int pos = atomicAdd(&cur[b], 1);
      stage[pos] = ((unsigned int)(d & 127) << 17) | (unsigned int)src[i];
    }
  }
}

__global__ void k_bucket(const unsigned int* __restrict__ stage, const int* __restrict__ boff,
                         int* __restrict__ csr, int* __restrict__ row_off,
                         float* __restrict__ dinv) {
  __shared__ int cnt[128], sc[128], cur[128];
  int b = blockIdx.x, t = threadIdx.x;
  int e0 = boff[b], e1 = boff[b + 1];
  if (t < 128) cnt[t] = 0;
  __syncthreads();
  for (int e = e0 + t; e < e1; e += 256)
    atomicAdd(&cnt[stage[e] >> 17], 1);
  __syncthreads();
  int myc = (t < 128) ? cnt[t] : 0;
  if (t < 128) sc[t] = myc;
  __syncthreads();
  for (int off = 1; off < 128; off <<= 1) {
    int a = (t < 128 && t >= off) ? sc[t - off] : 0;
    __syncthreads();
    if (t < 128) sc[t] += a;
    __syncthreads();
  }
  if (t < 128) {
    int node = b * 128 + t;
    int ex = sc[t] - myc;
    cur[t] = ex;
    if (node < N_NODES) {
      row_off[node] = e0 + ex;
      dinv[node] = myc ? 1.0f / (float)myc : 0.0f;
    }
  }
  if (b == NB - 1 && t == 0) row_off[N_NODES] = N_EDGES;
  __syncthreads();
  for (int e = e0 + t; e < e1; e += 256) {
    unsigned int v = stage[e];
    int l = v >> 17;
    int pos = e0 + atomicAdd(&cur[l], 1);
    csr[pos] = (int)(v & 0x1FFFFu);
  }
}

// ---------------- fp32 -> bf16 cast (x) ----------------
__global__ void k_cast(const float* __restrict__ x, unsigned short* __restrict__ xb) {
  int i = blockIdx.x * 256 + threadIdx.x;
  if (i >= N_NODES * 16) return;
  float4 a = ((const float4*)x)[2 * i];
  float4 b = ((const float4*)x)[2 * i + 1];
  unsigned short r[8] = {f2b(a.x), f2b(a.y), f2b(a.z), f2b(a.w),
                         f2b(b.x), f2b(b.y), f2b(b.z), f2b(b.w)};
  *(uint4*)(xb + (size_t)i * 8) = *(uint4*)r;
}

// ---------------- weight prep: bf16, transposed + K-concat ----------------
__global__ void k_wprep(const float* __restrict__ WS, const float* __restrict__ WN,
                        int nout, unsigned short* __restrict__ wt) {
  int t = blockIdx.x * 256 + threadIdx.x;
  if (t >= nout * 128) return;
  int n = t >> 7, k = t & 127;
  wt[n * 256 + k] = f2b(WS[(size_t)k * nout + n]);
  wt[n * 256 + 128 + k] = f2b(WN[(size_t)k * nout + n]);
}

// ---------------- aggregation: wave/node, 4 neighbor-slots x 16B chunks ----------------
__global__ void k_agg(const unsigned short* __restrict__ feat,
                      const int* __restrict__ row_off, const int* __restrict__ csr,
                      const float* __restrict__ dinv, unsigned short* __restrict__ nm) {
  int wv = threadIdx.x >> 6, lane = threadIdx.x & 63;
  int node = blockIdx.x * 4 + wv;
  if (node >= N_NODES) return;
  const uint4* fp = (const uint4*)feat;  // 16 uint4 per feature row
  int s0 = row_off[node], s1 = row_off[node + 1];
  int g = lane >> 4, c = lane & 15;
  float a0 = 0, a1 = 0, a2 = 0, a3 = 0, a4 = 0, a5 = 0, a6 = 0, a7 = 0;
  for (int j = s0; j < s1; j += 8) {
    int j0 = j + g, j1 = j + 4 + g;
    bool h0 = j0 < s1, h1 = j1 < s1;
    uint4 v0, v1;
    if (h0) v0 = fp[(size_t)csr[j0] * 16 + c];
    if (h1) v1 = fp[(size_t)csr[j1] * 16 + c];
    if (h0) {
      a0 += b2f(v0.x & 0xffffu); a1 += __uint_as_float(v0.x & 0xffff0000u);
      a2 += b2f(v0.y & 0xffffu); a3 += __uint_as_float(v0.y & 0xffff0000u);
      a4 += b2f(v0.z & 0xffffu); a5 += __uint_as_float(v0.z & 0xffff0000u);
      a6 += b2f(v0.w & 0xffffu); a7 += __uint_as_float(v0.w & 0xffff0000u);
    }
    if (h1) {
      a0 += b2f(v1.x & 0xffffu); a1 += __uint_as_float(v1.x & 0xffff0000u);
      a2 += b2f(v1.y & 0xffffu); a3 += __uint_as_float(v1.y & 0xffff0000u);
      a4 += b2f(v1.z & 0xffffu); a5 += __uint_as_float(v1.z & 0xffff0000u);
      a6 += b2f(v1.w & 0xffffu); a7 += __uint_as_float(v1.w & 0xffff0000u);
    }
  }
#define RED(x) x += __shfl_xor(x, 16); x += __shfl_xor(x, 32);
  RED(a0) RED(a1) RED(a2) RED(a3) RED(a4) RED(a5) RED(a6) RED(a7)
#undef RED
  if (g == 0) {
    float di = dinv[node];
    uint4 o;
    o.x = ((unsigned int)f2b(a1 * di) << 16) | (unsigned int)f2b(a0 * di);
    o.y = ((unsigned int)f2b(a3 * di) << 16) | (unsigned int)f2b(a2 * di);
    o.z = ((unsigned int)f2b(a5 * di) << 16) | (unsigned int)f2b(a4 * di);
    o.w = ((unsigned int)f2b(a7 * di) << 16) | (unsigned int)f2b(a6 * di);
    ((uint4*)(nm + (size_t)node * 128))[c] = o;
  }
}

// ---------------- MFMA GEMM: OUT = act([A0|A1] @ WT^T + B) ----------------
template <int NOUT, bool RELU, bool OUT_BF16>
__global__ __launch_bounds__(256, 4) void k_mm(
    const unsigned short* __restrict__ A0, const unsigned short* __restrict__ A1,
    const unsigned short* __restrict__ WT, const float* __restrict__ Bv,
    void* __restrict__ OUT) {
  constexpr int NFC = NOUT / 64;  // col-frags per wave
  __shared__ __align__(16) unsigned short sm[16896];  // 33792 B
  const int row0 = blockIdx.x * 64;
  const int tid = threadIdx.x;

  for (int i = tid; i < 1024; i += 256) {
    int r = i >> 4, c = i & 15;
    int gr = row0 + r;
    if (gr >= N_NODES) gr = N_NODES - 1;
    *(uint4*)(sm + r * 264 + c * 8) = ((const uint4*)(A0 + (size_t)gr * 128))[c];
    *(uint4*)(sm + r * 264 + 128 + c * 8) = ((const uint4*)(A1 + (size_t)gr * 128))[c];
  }

  const int lane = tid & 63;
  const int w = tid >> 6;
  const int r16 = lane & 15;
  const int kg = lane >> 4;
  const int wc0 = w * (NOUT / 4);

  f32x4 acc[4][NFC];
#pragma unroll
  for (int rf = 0; rf < 4; rf++)
#pragma unroll
    for (int cf = 0; cf < NFC; cf++) acc[rf][cf] = (f32x4){0.f, 0.f, 0.f, 0.f};

  __syncthreads();

  const unsigned short* wtb = WT + (size_t)(wc0 + r16) * 256 + kg * 8;
  const unsigned short* asb = sm + r16 * 264 + kg * 8;

  for (int ks = 0; ks < 8; ks++) {
    bf16x8 a[4];
#pragma unroll
    for (int rf = 0; rf < 4; rf++)
      a[rf] = *(const bf16x8*)(asb + rf * 16 * 264 + ks * 32);
#pragma unroll
    for (int cf = 0; cf < NFC; cf++) {
      bf16x8 b = *(const bf16x8*)(wtb + cf * 16 * 256 + ks * 32);
#pragma unroll
      for (int rf = 0; rf < 4; rf++)
        acc[rf][cf] = __builtin_amdgcn_mfma_f32_16x16x32_bf16(a[rf], b, acc[rf][cf], 0, 0, 0);
    }
  }

  __syncthreads();  // reuse sm for output staging

  if (OUT_BF16) {
    constexpr int LSO = NOUT + 8;
    unsigned short* so = sm;
#pragma unroll
    for (int rf = 0; rf < 4; rf++)
#pragma unroll
      for (int cf = 0; cf < NFC; cf++) {
        int col = wc0 + cf * 16 + r16;
        float bias = Bv[col];
#pragma unroll
        for (int r = 0; r < 4; r++) {
          int row = rf * 16 + kg * 4 + r;
          float v = acc[rf][cf][r] + bias;
          if (RELU) v = fmaxf(v, 0.f);
          so[row * LSO + col] = f2b(v);
        }
      }
    __syncthreads();
    unsigned short* O = (unsigned short*)OUT;
    for (int i = tid; i < 64 * (NOUT / 8); i += 256) {
      int r = i / (NOUT / 8), c = i % (NOUT / 8);
      int gr = row0 + r;
      if (gr < N_NODES)
        *(uint4*)(O + (size_t)gr * NOUT + c * 8) = *(const uint4*)(so + r * LSO + c * 8);
    }
  } else {
    constexpr int LSO = NOUT + 4;
    float* so = (float*)sm;
#pragma unroll
    for (int rf = 0; rf < 4; rf++)
#pragma unroll
      for (int cf = 0; cf < NFC; cf++) {
        int col = wc0 + cf * 16 + r16;
        float bias = Bv[col];
#pragma unroll
        for (int r = 0; r < 4; r++) {
          int row = rf * 16 + kg * 4 + r;
          float v = acc[rf][cf][r] + bias;
          if (RELU) v = fmaxf(v, 0.f);
          so[row * LSO + col] = v;
        }
      }
    __syncthreads();
    float* O = (float*)OUT;
    for (int i = tid; i < 64 * (NOUT / 4); i += 256) {
      int r = i / (NOUT / 4), c = i % (NOUT / 4);
      int gr = row0 + r;
      if (gr < N_NODES)
        *(float4*)(O + (size_t)gr * NOUT + c * 4) = *(const float4*)(so + r * LSO + c * 4);
    }
  }
}

// ---------------- launch ----------------

extern "C" void kernel_launch(void* const* d_in, const int* in_sizes, int n_in,
                              void* d_out, int out_size, void* d_ws, size_t ws_size,
                              hipStream_t stream) {
  const float* x   = (const float*)d_in[0];
  const int*   src = (const int*)d_in[1];
  const int*   dst = (const int*)d_in[2];
  const float* ws0 = (const float*)d_in[3];
  const float* wn0 = (const float*)d_in[4];
  const float* b0  = (const float*)d_in[5];
  const float* ws1 = (const float*)d_in[6];
  const float* wn1 = (const float*)d_in[7];
  const float* b1  = (const float*)d_in[8];
  const float* ws2 = (const float*)d_in[9];
  const float* wn2 = (const float*)d_in[10];
  const float* b2  = (const float*)d_in[11];
  float* out = (float*)d_out;

  uint8_t* base = (uint8_t*)d_ws;
  size_t off = 0;
  auto alloc = [&](size_t bytes) -> void* {
    void* p = base + off;
    off = (off + bytes + 255) & ~(size_t)255;
    return p;
  };
  int*   row_off = (int*)alloc((size_t)(N_NODES + 1) * 4);
  float* dinv    = (float*)alloc((size_t)N_NODES * 4);
  int*   csr     = (int*)alloc((size_t)N_EDGES * 4);
  unsigned int* stage = (unsigned int*)alloc((size_t)N_EDGES * 4);
  int*   bcount  = (int*)alloc((size_t)NB * 4);
  int*   boff    = (int*)alloc((size_t)(NB + 1) * 4);
  int*   bcursor = (int*)alloc((size_t)NB * 4);
  unsigned short* xb  = (unsigned short*)alloc((size_t)N_NODES * 128 * 2);
  unsigned short* nmb = (unsigned short*)alloc((size_t)N_NODES * 128 * 2);
  unsigned short* h1b = (unsigned short*)alloc((size_t)N_NODES * 128 * 2);
  unsigned short* h2b = (unsigned short*)alloc((size_t)N_NODES * 128 * 2);
  unsigned short* wt0 = (unsigned short*)alloc(128 * 256 * 2);
  unsigned short* wt1 = (unsigned short*)alloc(128 * 256 * 2);
  unsigned short* wt2 = (unsigned short*)alloc(64 * 256 * 2);

  hipMemsetAsync(bcount, 0, (size_t)NB * 4, stream);
  k_hist<<<(N_EDGES + 4095) / 4096, 256, 0, stream>>>(dst, bcount);
  k_bscan<<<1, 1024, 0, stream>>>(bcount, boff, bcursor);
  k_scatter<<<(N_EDGES + EPB - 1) / EPB, 256, 0, stream>>>(src, dst, bcursor, stage);
  k_bucket<<<NB, 256, 0, stream>>>(stage, boff, csr, row_off, dinv);

  k_cast<<<(N_NODES * 16 + 255) / 256, 256, 0, stream>>>(x, xb);
  k_wprep<<<64, 256, 0, stream>>>(ws0, wn0, 128, wt0);
  k_wprep<<<64, 256, 0, stream>>>(ws1, wn1, 128, wt1);
  k_wprep<<<32, 256, 0, stream>>>(ws2, wn2, 64, wt2);

  const int GMM = (N_NODES + 63) / 64;  // 1563

  // layer 0
  k_agg<<<25000, 256, 0, stream>>>(xb, row_off, csr, dinv, nmb);
  k_mm<128, true, true><<<GMM, 256, 0, stream>>>(xb, nmb, wt0, b0, h1b);
  // layer 1
  k_agg<<<25000, 256, 0, stream>>>(h1b, row_off, csr, dinv, nmb);
  k_mm<128, true, true><<<GMM, 256, 0, stream>>>(h1b, nmb, wt1, b1, h2b);
  // layer 2
  k_agg<<<25000, 256, 0, stream>>>(h2b, row_off, csr, dinv, nmb);
  k_mm<64, false, false><<<GMM, 256, 0, stream>>>(h2b, nmb, wt2, b2, out);
}

// Round 5
// 295.249 us; speedup vs baseline: 4.4629x; 1.1210x over previous
//
#include <hip/hip_runtime.h>
#include <stdint.h>

#define N_NODES 100000
#define N_EDGES 1000000
#define NB 782  // ceil(N_NODES/128) buckets of 128 nodes

typedef __attribute__((ext_vector_type(8))) short bf16x8;
typedef __attribute__((ext_vector_type(4))) float f32x4;

__device__ __forceinline__ unsigned short f2b(float f) {
  unsigned int u = __float_as_uint(f);
  unsigned int r = (u + 0x7fffu + ((u >> 16) & 1u)) >> 16;
  return (unsigned short)r;
}
__device__ __forceinline__ float b2f(unsigned int lo16) {
  return __uint_as_float(lo16 << 16);
}

// ---------------- bucketed CSR build ----------------

__global__ void k_hist(const int* __restrict__ dst, int* __restrict__ bcount) {
  __shared__ int h[NB];
  int t = threadIdx.x;
  for (int i = t; i < NB; i += 256) h[i] = 0;
  __syncthreads();
  int base = blockIdx.x * 4096;
#pragma unroll
  for (int k = 0; k < 16; k++) {
    int i = base + t + k * 256;
    if (i < N_EDGES) atomicAdd(&h[dst[i] >> 7], 1);
  }
  __syncthreads();
  for (int i = t; i < NB; i += 256)
    if (h[i]) atomicAdd(&bcount[i], h[i]);
}

__global__ __launch_bounds__(1024) void k_bscan(const int* __restrict__ bcount,
                                                int* __restrict__ boff,
                                                int* __restrict__ bcursor) {
  __shared__ int sc[1024];
  int t = threadIdx.x;
  int v = (t < NB) ? bcount[t] : 0;
  sc[t] = v;
  __syncthreads();
  for (int off = 1; off < 1024; off <<= 1) {
    int a = (t >= off) ? sc[t - off] : 0;
    __syncthreads();
    sc[t] += a;
    __syncthreads();
  }
  if (t < NB) {
    boff[t + 1] = sc[t];
    bcursor[t] = sc[t] - v;
  }
  if (t == 0) boff[0] = 0;
}

#define EPB 4096  // edges per scatter block -> 245 workgroups
__global__ void k_scatter(const int* __restrict__ src, const int* __restrict__ dst,
                          int* __restrict__ bcursor, unsigned int* __restrict__ stage) {
  __shared__ int h[NB];
  __shared__ int cur[NB];
  int t = threadIdx.x;
  for (int i = t; i < NB; i += 256) h[i] = 0;
  __syncthreads();
  int base = blockIdx.x * EPB;
#pragma unroll 4
  for (int k = 0; k < EPB / 256; k++) {
    int i = base + t + k * 256;
    if (i < N_EDGES) atomicAdd(&h[dst[i] >> 7], 1);
  }
  __syncthreads();
  for (int i = t; i < NB; i += 256) {
    int c = h[i];
    cur[i] = c ? atomicAdd(&bcursor[i], c) : 0;
  }
  __syncthreads();
#pragma unroll 4
  for (int k = 0; k < EPB / 256; k++) {
    int i = base + t + k * 256;
    if (i < N_EDGES) {
      int d = dst[i];
      int b = d >> 7;
      int pos = atomicAdd(&cur[b], 1);
      stage[pos] = ((unsigned int)(d & 127) << 17) | (unsigned int)src[i];
    }
  }
}

__global__ void k_bucket(const unsigned int* __restrict__ stage, const int* __restrict__ boff,
                         int* __restrict__ csr, int* __restrict__ row_off,
                         float* __restrict__ dinv) {
  __shared__ int cnt[128], sc[128], cur[128];
  int b = blockIdx.x, t = threadIdx.x;
  int e0 = boff[b], e1 = boff[b + 1];
  if (t < 128) cnt[t] = 0;
  __syncthreads();
  for (int e = e0 + t; e < e1; e += 256)
    atomicAdd(&cnt[stage[e] >> 17], 1);
  __syncthreads();
  int myc = (t < 128) ? cnt[t] : 0;
  if (t < 128) sc[t] = myc;
  __syncthreads();
  for (int off = 1; off < 128; off <<= 1) {
    int a = (t < 128 && t >= off) ? sc[t - off] : 0;
    __syncthreads();
    if (t < 128) sc[t] += a;
    __syncthreads();
  }
  if (t < 128) {
    int node = b * 128 + t;
    int ex = sc[t] - myc;
    cur[t] = ex;
    if (node < N_NODES) {
      row_off[node] = e0 + ex;
      dinv[node] = myc ? 1.0f / (float)myc : 0.0f;
    }
  }
  if (b == NB - 1 && t == 0) row_off[N_NODES] = N_EDGES;
  __syncthreads();
  for (int e = e0 + t; e < e1; e += 256) {
    unsigned int v = stage[e];
    int l = v >> 17;
    int pos = e0 + atomicAdd(&cur[l], 1);
    csr[pos] = (int)(v & 0x1FFFFu);
  }
}

// ---------------- fp32 -> bf16 cast (x) ----------------
__global__ void k_cast(const float* __restrict__ x, unsigned short* __restrict__ xb) {
  int i = blockIdx.x * 256 + threadIdx.x;
  if (i >= N_NODES * 16) return;
  float4 a = ((const float4*)x)[2 * i];
  float4 b = ((const float4*)x)[2 * i + 1];
  unsigned short r[8] = {f2b(a.x), f2b(a.y), f2b(a.z), f2b(a.w),
                         f2b(b.x), f2b(b.y), f2b(b.z), f2b(b.w)};
  *(uint4*)(xb + (size_t)i * 8) = *(uint4*)r;
}

// ---------------- weight prep: bf16, transposed + K-concat ----------------
__global__ void k_wprep(const float* __restrict__ WS, const float* __restrict__ WN,
                        int nout, unsigned short* __restrict__ wt) {
  int t = blockIdx.x * 256 + threadIdx.x;
  if (t >= nout * 128) return;
  int n = t >> 7, k = t & 127;
  wt[n * 256 + k] = f2b(WS[(size_t)k * nout + n]);
  wt[n * 256 + 128 + k] = f2b(WN[(size_t)k * nout + n]);
}

// ---------------- aggregation: wave/node, 4 neighbor-slots x 16B chunks ----------------
__global__ void k_agg(const unsigned short* __restrict__ feat,
                      const int* __restrict__ row_off, const int* __restrict__ csr,
                      const float* __restrict__ dinv, unsigned short* __restrict__ nm) {
  int wv = threadIdx.x >> 6, lane = threadIdx.x & 63;
  int node = blockIdx.x * 4 + wv;
  if (node >= N_NODES) return;
  const uint4* fp = (const uint4*)feat;  // 16 uint4 per feature row
  int s0 = row_off[node], s1 = row_off[node + 1];
  int g = lane >> 4, c = lane & 15;
  float a0 = 0, a1 = 0, a2 = 0, a3 = 0, a4 = 0, a5 = 0, a6 = 0, a7 = 0;
  for (int j = s0; j < s1; j += 8) {
    int j0 = j + g, j1 = j + 4 + g;
    bool h0 = j0 < s1, h1 = j1 < s1;
    uint4 v0, v1;
    if (h0) v0 = fp[(size_t)csr[j0] * 16 + c];
    if (h1) v1 = fp[(size_t)csr[j1] * 16 + c];
    if (h0) {
      a0 += b2f(v0.x & 0xffffu); a1 += __uint_as_float(v0.x & 0xffff0000u);
      a2 += b2f(v0.y & 0xffffu); a3 += __uint_as_float(v0.y & 0xffff0000u);
      a4 += b2f(v0.z & 0xffffu); a5 += __uint_as_float(v0.z & 0xffff0000u);
      a6 += b2f(v0.w & 0xffffu); a7 += __uint_as_float(v0.w & 0xffff0000u);
    }
    if (h1) {
      a0 += b2f(v1.x & 0xffffu); a1 += __uint_as_float(v1.x & 0xffff0000u);
      a2 += b2f(v1.y & 0xffffu); a3 += __uint_as_float(v1.y & 0xffff0000u);
      a4 += b2f(v1.z & 0xffffu); a5 += __uint_as_float(v1.z & 0xffff0000u);
      a6 += b2f(v1.w & 0xffffu); a7 += __uint_as_float(v1.w & 0xffff0000u);
    }
  }
#define RED(x) x += __shfl_xor(x, 16); x += __shfl_xor(x, 32);
  RED(a0) RED(a1) RED(a2) RED(a3) RED(a4) RED(a5) RED(a6) RED(a7)
#undef RED
  if (g == 0) {
    float di = dinv[node];
    uint4 o;
    o.x = ((unsigned int)f2b(a1 * di) << 16) | (unsigned int)f2b(a0 * di);
    o.y = ((unsigned int)f2b(a3 * di) << 16) | (unsigned int)f2b(a2 * di);
    o.z = ((unsigned int)f2b(a5 * di) << 16) | (unsigned int)f2b(a4 * di);
    o.w = ((unsigned int)f2b(a7 * di) << 16) | (unsigned int)f2b(a6 * di);
    ((uint4*)(nm + (size_t)node * 128))[c] = o;
  }
}

// ---------------- MFMA GEMM: OUT = act([A0|A1] @ WT^T + B) ----------------
template <int NOUT, bool RELU, bool OUT_BF16>
__global__ __launch_bounds__(256, 4) void k_mm(
    const unsigned short* __restrict__ A0, const unsigned short* __restrict__ A1,
    const unsigned short* __restrict__ WT, const float* __restrict__ Bv,
    void* __restrict__ OUT) {
  constexpr int NFC = NOUT / 64;  // col-frags per wave
  __shared__ __align__(16) unsigned short sm[16896];  // 33792 B
  const int row0 = blockIdx.x * 64;
  const int tid = threadIdx.x;

  for (int i = tid; i < 1024; i += 256) {
    int r = i >> 4, c = i & 15;
    int gr = row0 + r;
    if (gr >= N_NODES) gr = N_NODES - 1;
    *(uint4*)(sm + r * 264 + c * 8) = ((const uint4*)(A0 + (size_t)gr * 128))[c];
    *(uint4*)(sm + r * 264 + 128 + c * 8) = ((const uint4*)(A1 + (size_t)gr * 128))[c];
  }

  const int lane = tid & 63;
  const int w = tid >> 6;
  const int r16 = lane & 15;
  const int kg = lane >> 4;
  const int wc0 = w * (NOUT / 4);

  f32x4 acc[4][NFC];
#pragma unroll
  for (int rf = 0; rf < 4; rf++)
#pragma unroll
    for (int cf = 0; cf < NFC; cf++) acc[rf][cf] = (f32x4){0.f, 0.f, 0.f, 0.f};

  __syncthreads();

  const unsigned short* wtb = WT + (size_t)(wc0 + r16) * 256 + kg * 8;
  const unsigned short* asb = sm + r16 * 264 + kg * 8;

  for (int ks = 0; ks < 8; ks++) {
    bf16x8 a[4];
#pragma unroll
    for (int rf = 0; rf < 4; rf++)
      a[rf] = *(const bf16x8*)(asb + rf * 16 * 264 + ks * 32);
#pragma unroll
    for (int cf = 0; cf < NFC; cf++) {
      bf16x8 b = *(const bf16x8*)(wtb + cf * 16 * 256 + ks * 32);
#pragma unroll
      for (int rf = 0; rf < 4; rf++)
        acc[rf][cf] = __builtin_amdgcn_mfma_f32_16x16x32_bf16(a[rf], b, acc[rf][cf], 0, 0, 0);
    }
  }

  __syncthreads();  // reuse sm for output staging

  if (OUT_BF16) {
    constexpr int LSO = NOUT + 8;
    unsigned short* so = sm;
#pragma unroll
    for (int rf = 0; rf < 4; rf++)
#pragma unroll
      for (int cf = 0; cf < NFC; cf++) {
        int col = wc0 + cf * 16 + r16;
        float bias = Bv[col];
#pragma unroll
        for (int r = 0; r < 4; r++) {
          int row = rf * 16 + kg * 4 + r;
          float v = acc[rf][cf][r] + bias;
          if (RELU) v = fmaxf(v, 0.f);
          so[row * LSO + col] = f2b(v);
        }
      }
    __syncthreads();
    unsigned short* O = (unsigned short*)OUT;
    for (int i = tid; i < 64 * (NOUT / 8); i += 256) {
      int r = i / (NOUT / 8), c = i % (NOUT / 8);
      int gr = row0 + r;
      if (gr < N_NODES)
        *(uint4*)(O + (size_t)gr * NOUT + c * 8) = *(const uint4*)(so + r * LSO + c * 8);
    }
  } else {
    constexpr int LSO = NOUT + 4;
    float* so = (float*)sm;
#pragma unroll
    for (int rf = 0; rf < 4; rf++)
#pragma unroll
      for (int cf = 0; cf < NFC; cf++) {
        int col = wc0 + cf * 16 + r16;
        float bias = Bv[col];
#pragma unroll
        for (int r = 0; r < 4; r++) {
          int row = rf * 16 + kg * 4 + r;
          float v = acc[rf][cf][r] + bias;
          if (RELU) v = fmaxf(v, 0.f);
          so[row * LSO + col] = v;
        }
      }
    __syncthreads();
    float* O = (float*)OUT;
    for (int i = tid; i < 64 * (NOUT / 4); i += 256) {
      int r = i / (NOUT / 4), c = i % (NOUT / 4);
      int gr = row0 + r;
      if (gr < N_NODES)
        *(float4*)(O + (size_t)gr * NOUT + c * 4) = *(const float4*)(so + r * LSO + c * 4);
    }
  }
}

// ---------------- launch ----------------

extern "C" void kernel_launch(void* const* d_in, const int* in_sizes, int n_in,
                              void* d_out, int out_size, void* d_ws, size_t ws_size,
                              hipStream_t stream) {
  const float* x   = (const float*)d_in[0];
  const int*   src = (const int*)d_in[1];
  const int*   dst = (const int*)d_in[2];
  const float* ws0 = (const float*)d_in[3];
  const float* wn0 = (const float*)d_in[4];
  const float* b0  = (const float*)d_in[5];
  const float* ws1 = (const float*)d_in[6];
  const float* wn1 = (const float*)d_in[7];
  const float* b1  = (const float*)d_in[8];
  const float* ws2 = (const float*)d_in[9];
  const float* wn2 = (const float*)d_in[10];
  const float* b2  = (const float*)d_in[11];
  float* out = (float*)d_out;

  uint8_t* base = (uint8_t*)d_ws;
  size_t off = 0;
  auto alloc = [&](size_t bytes) -> void* {
    void* p = base + off;
    off = (off + bytes + 255) & ~(size_t)255;
    return p;
  };
  int*   row_off = (int*)alloc((size_t)(N_NODES + 1) * 4);
  float* dinv    = (float*)alloc((size_t)N_NODES * 4);
  int*   csr     = (int*)alloc((size_t)N_EDGES * 4);
  unsigned int* stage = (unsigned int*)alloc((size_t)N_EDGES * 4);
  int*   bcount  = (int*)alloc((size_t)NB * 4);
  int*   boff    = (int*)alloc((size_t)(NB + 1) * 4);
  int*   bcursor = (int*)alloc((size_t)NB * 4);
  unsigned short* xb  = (unsigned short*)alloc((size_t)N_NODES * 128 * 2);
  unsigned short* nmb = (unsigned short*)alloc((size_t)N_NODES * 128 * 2);
  unsigned short* h1b = (unsigned short*)alloc((size_t)N_NODES * 128 * 2);
  unsigned short* h2b = (unsigned short*)alloc((size_t)N_NODES * 128 * 2);
  unsigned short* wt0 = (unsigned short*)alloc(128 * 256 * 2);
  unsigned short* wt1 = (unsigned short*)alloc(128 * 256 * 2);
  unsigned short* wt2 = (unsigned short*)alloc(64 * 256 * 2);

  hipMemsetAsync(bcount, 0, (size_t)NB * 4, stream);
  k_hist<<<(N_EDGES + 4095) / 4096, 256, 0, stream>>>(dst, bcount);
  k_bscan<<<1, 1024, 0, stream>>>(bcount, boff, bcursor);
  k_scatter<<<(N_EDGES + EPB - 1) / EPB, 256, 0, stream>>>(src, dst, bcursor, stage);
  k_bucket<<<NB, 256, 0, stream>>>(stage, boff, csr, row_off, dinv);

  k_cast<<<(N_NODES * 16 + 255) / 256, 256, 0, stream>>>(x, xb);
  k_wprep<<<64, 256, 0, stream>>>(ws0, wn0, 128, wt0);
  k_wprep<<<64, 256, 0, stream>>>(ws1, wn1, 128, wt1);
  k_wprep<<<32, 256, 0, stream>>>(ws2, wn2, 64, wt2);

  const int GMM = (N_NODES + 63) / 64;  // 1563

  // layer 0
  k_agg<<<25000, 256, 0, stream>>>(xb, row_off, csr, dinv, nmb);
  k_mm<128, true, true><<<GMM, 256, 0, stream>>>(xb, nmb, wt0, b0, h1b);
  // layer 1
  k_agg<<<25000, 256, 0, stream>>>(h1b, row_off, csr, dinv, nmb);
  k_mm<128, true, true><<<GMM, 256, 0, stream>>>(h1b, nmb, wt1, b1, h2b);
  // layer 2
  k_agg<<<25000, 256, 0, stream>>>(h2b, row_off, csr, dinv, nmb);
  k_mm<64, false, false><<<GMM, 256, 0, stream>>>(h2b, nmb, wt2, b2, out);
}

// Round 6
// 269.569 us; speedup vs baseline: 4.8881x; 1.0953x over previous
//
#include <hip/hip_runtime.h>
#include <stdint.h>

#define N_NODES 100000
#define N_EDGES 1000000
#define NB 782  // ceil(N_NODES/128) buckets of 128 nodes

typedef __attribute__((ext_vector_type(8))) short bf16x8;
typedef __attribute__((ext_vector_type(4))) float f32x4;

__device__ __forceinline__ unsigned short f2b(float f) {
  unsigned int u = __float_as_uint(f);
  unsigned int r = (u + 0x7fffu + ((u >> 16) & 1u)) >> 16;
  return (unsigned short)r;
}
__device__ __forceinline__ float b2f(unsigned int lo16) {
  return __uint_as_float(lo16 << 16);
}

// ---------------- bucketed CSR build ----------------

__global__ void k_hist(const int* __restrict__ dst, int* __restrict__ bcount) {
  __shared__ int h[NB];
  int t = threadIdx.x;
  for (int i = t; i < NB; i += 256) h[i] = 0;
  __syncthreads();
  int base = blockIdx.x * 4096;
#pragma unroll
  for (int k = 0; k < 16; k++) {
    int i = base + t + k * 256;
    if (i < N_EDGES) atomicAdd(&h[dst[i] >> 7], 1);
  }
  __syncthreads();
  for (int i = t; i < NB; i += 256)
    if (h[i]) atomicAdd(&bcount[i], h[i]);
}

__global__ __launch_bounds__(1024) void k_bscan(const int* __restrict__ bcount,
                                                int* __restrict__ boff,
                                                int* __restrict__ bcursor) {
  __shared__ int sc[1024];
  int t = threadIdx.x;
  int v = (t < NB) ? bcount[t] : 0;
  sc[t] = v;
  __syncthreads();
  for (int off = 1; off < 1024; off <<= 1) {
    int a = (t >= off) ? sc[t - off] : 0;
    __syncthreads();
    sc[t] += a;
    __syncthreads();
  }
  if (t < NB) {
    boff[t + 1] = sc[t];
    bcursor[t] = sc[t] - v;
  }
  if (t == 0) boff[0] = 0;
}

#define EPB 4096  // edges per scatter block -> 245 workgroups
__global__ void k_scatter(const int* __restrict__ src, const int* __restrict__ dst,
                          int* __restrict__ bcursor, unsigned int* __restrict__ stage) {
  __shared__ int h[NB];
  __shared__ int cur[NB];
  int t = threadIdx.x;
  for (int i = t; i < NB; i += 256) h[i] = 0;
  __syncthreads();
  int base = blockIdx.x * EPB;
#pragma unroll 4
  for (int k = 0; k < EPB / 256; k++) {
    int i = base + t + k * 256;
    if (i < N_EDGES) atomicAdd(&h[dst[i] >> 7], 1);
  }
  __syncthreads();
  for (int i = t; i < NB; i += 256) {
    int c = h[i];
    cur[i] = c ? atomicAdd(&bcursor[i], c) : 0;
  }
  __syncthreads();
#pragma unroll 4
  for (int k = 0; k < EPB / 256; k++) {
    int i = base + t + k * 256;
    if (i < N_EDGES) {
      int d = dst[i];
      int b = d >> 7;
      int pos = atomicAdd(&cur[b], 1);
      stage[pos] = ((unsigned int)(d & 127) << 17) | (unsigned int)src[i];
    }
  }
}

__global__ void k_bucket(const unsigned int* __restrict__ stage, const int* __restrict__ boff,
                         int* __restrict__ csr, int* __restrict__ row_off,
                         float* __restrict__ dinv) {
  __shared__ int cnt[128], sc[128], cur[128];
  int b = blockIdx.x, t = threadIdx.x;
  int e0 = boff[b], e1 = boff[b + 1];
  if (t < 128) cnt[t] = 0;
  __syncthreads();
  for (int e = e0 + t; e < e1; e += 256)
    atomicAdd(&cnt[stage[e] >> 17], 1);
  __syncthreads();
  int myc = (t < 128) ? cnt[t] : 0;
  if (t < 128) sc[t] = myc;
  __syncthreads();
  for (int off = 1; off < 128; off <<= 1) {
    int a = (t < 128 && t >= off) ? sc[t - off] : 0;
    __syncthreads();
    if (t < 128) sc[t] += a;
    __syncthreads();
  }
  if (t < 128) {
    int node = b * 128 + t;
    int ex = sc[t] - myc;
    cur[t] = ex;
    if (node < N_NODES) {
      row_off[node] = e0 + ex;
      dinv[node] = myc ? 1.0f / (float)myc : 0.0f;
    }
  }
  if (b == NB - 1 && t == 0) row_off[N_NODES] = N_EDGES;
  __syncthreads();
  for (int e = e0 + t; e < e1; e += 256) {
    unsigned int v = stage[e];
    int l = v >> 17;
    int pos = e0 + atomicAdd(&cur[l], 1);
    csr[pos] = (int)(v & 0x1FFFFu);
  }
}

// ---------------- fp32 -> bf16 cast (x) ----------------
__global__ void k_cast(const float* __restrict__ x, unsigned short* __restrict__ xb) {
  int i = blockIdx.x * 256 + threadIdx.x;
  if (i >= N_NODES * 16) return;
  float4 a = ((const float4*)x)[2 * i];
  float4 b = ((const float4*)x)[2 * i + 1];
  unsigned short r[8] = {f2b(a.x), f2b(a.y), f2b(a.z), f2b(a.w),
                         f2b(b.x), f2b(b.y), f2b(b.z), f2b(b.w)};
  *(uint4*)(xb + (size_t)i * 8) = *(uint4*)r;
}

// ---------------- weight prep: bf16, transposed + K-concat ----------------
__global__ void k_wprep(const float* __restrict__ WS, const float* __restrict__ WN,
                        int nout, unsigned short* __restrict__ wt) {
  int t = blockIdx.x * 256 + threadIdx.x;
  if (t >= nout * 128) return;
  int n = t >> 7, k = t & 127;
  wt[n * 256 + k] = f2b(WS[(size_t)k * nout + n]);
  wt[n * 256 + 128 + k] = f2b(WN[(size_t)k * nout + n]);
}

// ---------------- aggregation: wave/node, 16 neighbor-slots in flight ----------------
__global__ void k_agg(const unsigned short* __restrict__ feat,
                      const int* __restrict__ row_off, const int* __restrict__ csr,
                      const float* __restrict__ dinv, unsigned short* __restrict__ nm) {
  int wv = threadIdx.x >> 6, lane = threadIdx.x & 63;
  int node = blockIdx.x * 4 + wv;
  if (node >= N_NODES) return;
  const uint4* fp = (const uint4*)feat;  // 16 uint4 per feature row
  int s0 = row_off[node], s1 = row_off[node + 1];
  int g = lane >> 4, c = lane & 15;
  float a0 = 0, a1 = 0, a2 = 0, a3 = 0, a4 = 0, a5 = 0, a6 = 0, a7 = 0;
  // 4 lane-groups x 4 slots = 16 neighbors per iteration; all index loads
  // issue first, then all feature gathers -> 4 independent chains per lane.
  for (int j = s0 + g; j < s1; j += 16) {
    int i1 = j + 4, i2 = j + 8, i3 = j + 12;
    bool h1 = i1 < s1, h2 = i2 < s1, h3 = i3 < s1;
    int c0 = csr[j];
    int c1 = h1 ? csr[i1] : 0;
    int c2 = h2 ? csr[i2] : 0;
    int c3 = h3 ? csr[i3] : 0;
    uint4 v0, v1, v2, v3;
    v0 = fp[(size_t)c0 * 16 + c];
    if (h1) v1 = fp[(size_t)c1 * 16 + c];
    if (h2) v2 = fp[(size_t)c2 * 16 + c];
    if (h3) v3 = fp[(size_t)c3 * 16 + c];
    {
      a0 += b2f(v0.x & 0xffffu); a1 += __uint_as_float(v0.x & 0xffff0000u);
      a2 += b2f(v0.y & 0xffffu); a3 += __uint_as_float(v0.y & 0xffff0000u);
      a4 += b2f(v0.z & 0xffffu); a5 += __uint_as_float(v0.z & 0xffff0000u);
      a6 += b2f(v0.w & 0xffffu); a7 += __uint_as_float(v0.w & 0xffff0000u);
    }
    if (h1) {
      a0 += b2f(v1.x & 0xffffu); a1 += __uint_as_float(v1.x & 0xffff0000u);
      a2 += b2f(v1.y & 0xffffu); a3 += __uint_as_float(v1.y & 0xffff0000u);
      a4 += b2f(v1.z & 0xffffu); a5 += __uint_as_float(v1.z & 0xffff0000u);
      a6 += b2f(v1.w & 0xffffu); a7 += __uint_as_float(v1.w & 0xffff0000u);
    }
    if (h2) {
      a0 += b2f(v2.x & 0xffffu); a1 += __uint_as_float(v2.x & 0xffff0000u);
      a2 += b2f(v2.y & 0xffffu); a3 += __uint_as_float(v2.y & 0xffff0000u);
      a4 += b2f(v2.z & 0xffffu); a5 += __uint_as_float(v2.z & 0xffff0000u);
      a6 += b2f(v2.w & 0xffffu); a7 += __uint_as_float(v2.w & 0xffff0000u);
    }
    if (h3) {
      a0 += b2f(v3.x & 0xffffu); a1 += __uint_as_float(v3.x & 0xffff0000u);
      a2 += b2f(v3.y & 0xffffu); a3 += __uint_as_float(v3.y & 0xffff0000u);
      a4 += b2f(v3.z & 0xffffu); a5 += __uint_as_float(v3.z & 0xffff0000u);
      a6 += b2f(v3.w & 0xffffu); a7 += __uint_as_float(v3.w & 0xffff0000u);
    }
  }
#define RED(x) x += __shfl_xor(x, 16); x += __shfl_xor(x, 32);
  RED(a0) RED(a1) RED(a2) RED(a3) RED(a4) RED(a5) RED(a6) RED(a7)
#undef RED
  if (g == 0) {
    float di = dinv[node];
    uint4 o;
    o.x = ((unsigned int)f2b(a1 * di) << 16) | (unsigned int)f2b(a0 * di);
    o.y = ((unsigned int)f2b(a3 * di) << 16) | (unsigned int)f2b(a2 * di);
    o.z = ((unsigned int)f2b(a5 * di) << 16) | (unsigned int)f2b(a4 * di);
    o.w = ((unsigned int)f2b(a7 * di) << 16) | (unsigned int)f2b(a6 * di);
    ((uint4*)(nm + (size_t)node * 128))[c] = o;
  }
}

// ---------------- MFMA GEMM: OUT = act([A0|A1] @ WT^T + B) ----------------
template <int NOUT, bool RELU, bool OUT_BF16>
__global__ __launch_bounds__(256, 4) void k_mm(
    const unsigned short* __restrict__ A0, const unsigned short* __restrict__ A1,
    const unsigned short* __restrict__ WT, const float* __restrict__ Bv,
    void* __restrict__ OUT) {
  constexpr int NFC = NOUT / 64;  // col-frags per wave
  __shared__ __align__(16) unsigned short sm[16896];  // 33792 B
  const int row0 = blockIdx.x * 64;
  const int tid = threadIdx.x;

  for (int i = tid; i < 1024; i += 256) {
    int r = i >> 4, c = i & 15;
    int gr = row0 + r;
    if (gr >= N_NODES) gr = N_NODES - 1;
    *(uint4*)(sm + r * 264 + c * 8) = ((const uint4*)(A0 + (size_t)gr * 128))[c];
    *(uint4*)(sm + r * 264 + 128 + c * 8) = ((const uint4*)(A1 + (size_t)gr * 128))[c];
  }

  const int lane = tid & 63;
  const int w = tid >> 6;
  const int r16 = lane & 15;
  const int kg = lane >> 4;
  const int wc0 = w * (NOUT / 4);

  f32x4 acc[4][NFC];
#pragma unroll
  for (int rf = 0; rf < 4; rf++)
#pragma unroll
    for (int cf = 0; cf < NFC; cf++) acc[rf][cf] = (f32x4){0.f, 0.f, 0.f, 0.f};

  __syncthreads();

  const unsigned short* wtb = WT + (size_t)(wc0 + r16) * 256 + kg * 8;
  const unsigned short* asb = sm + r16 * 264 + kg * 8;

  for (int ks = 0; ks < 8; ks++) {
    bf16x8 a[4];
#pragma unroll
    for (int rf = 0; rf < 4; rf++)
      a[rf] = *(const bf16x8*)(asb + rf * 16 * 264 + ks * 32);
#pragma unroll
    for (int cf = 0; cf < NFC; cf++) {
      bf16x8 b = *(const bf16x8*)(wtb + cf * 16 * 256 + ks * 32);
#pragma unroll
      for (int rf = 0; rf < 4; rf++)
        acc[rf][cf] = __builtin_amdgcn_mfma_f32_16x16x32_bf16(a[rf], b, acc[rf][cf], 0, 0, 0);
    }
  }

  __syncthreads();  // reuse sm for output staging

  if (OUT_BF16) {
    constexpr int LSO = NOUT + 8;
    unsigned short* so = sm;
#pragma unroll
    for (int rf = 0; rf < 4; rf++)
#pragma unroll
      for (int cf = 0; cf < NFC; cf++) {
        int col = wc0 + cf * 16 + r16;
        float bias = Bv[col];
#pragma unroll
        for (int r = 0; r < 4; r++) {
          int row = rf * 16 + kg * 4 + r;
          float v = acc[rf][cf][r] + bias;
          if (RELU) v = fmaxf(v, 0.f);
          so[row * LSO + col] = f2b(v);
        }
      }
    __syncthreads();
    unsigned short* O = (unsigned short*)OUT;
    for (int i = tid; i < 64 * (NOUT / 8); i += 256) {
      int r = i / (NOUT / 8), c = i % (NOUT / 8);
      int gr = row0 + r;
      if (gr < N_NODES)
        *(uint4*)(O + (size_t)gr * NOUT + c * 8) = *(const uint4*)(so + r * LSO + c * 8);
    }
  } else {
    constexpr int LSO = NOUT + 4;
    float* so = (float*)sm;
#pragma unroll
    for (int rf = 0; rf < 4; rf++)
#pragma unroll
      for (int cf = 0; cf < NFC; cf++) {
        int col = wc0 + cf * 16 + r16;
        float bias = Bv[col];
#pragma unroll
        for (int r = 0; r < 4; r++) {
          int row = rf * 16 + kg * 4 + r;
          float v = acc[rf][cf][r] + bias;
          if (RELU) v = fmaxf(v, 0.f);
          so[row * LSO + col] = v;
        }
      }
    __syncthreads();
    float* O = (float*)OUT;
    for (int i = tid; i < 64 * (NOUT / 4); i += 256) {
      int r = i / (NOUT / 4), c = i % (NOUT / 4);
      int gr = row0 + r;
      if (gr < N_NODES)
        *(float4*)(O + (size_t)gr * NOUT + c * 4) = *(const float4*)(so + r * LSO + c * 4);
    }
  }
}

// ---------------- launch ----------------

extern "C" void kernel_launch(void* const* d_in, const int* in_sizes, int n_in,
                              void* d_out, int out_size, void* d_ws, size_t ws_size,
                              hipStream_t stream) {
  const float* x   = (const float*)d_in[0];
  const int*   src = (const int*)d_in[1];
  const int*   dst = (const int*)d_in[2];
  const float* ws0 = (const float*)d_in[3];
  const float* wn0 = (const float*)d_in[4];
  const float* b0  = (const float*)d_in[5];
  const float* ws1 = (const float*)d_in[6];
  const float* wn1 = (const float*)d_in[7];
  const float* b1  = (const float*)d_in[8];
  const float* ws2 = (const float*)d_in[9];
  const float* wn2 = (const float*)d_in[10];
  const float* b2  = (const float*)d_in[11];
  float* out = (float*)d_out;

  uint8_t* base = (uint8_t*)d_ws;
  size_t off = 0;
  auto alloc = [&](size_t bytes) -> void* {
    void* p = base + off;
    off = (off + bytes + 255) & ~(size_t)255;
    return p;
  };
  int*   row_off = (int*)alloc((size_t)(N_NODES + 1) * 4);
  float* dinv    = (float*)alloc((size_t)N_NODES * 4);
  int*   csr     = (int*)alloc((size_t)N_EDGES * 4);
  unsigned int* stage = (unsigned int*)alloc((size_t)N_EDGES * 4);
  int*   bcount  = (int*)alloc((size_t)NB * 4);
  int*   boff    = (int*)alloc((size_t)(NB + 1) * 4);
  int*   bcursor = (int*)alloc((size_t)NB * 4);
  unsigned short* xb  = (unsigned short*)alloc((size_t)N_NODES * 128 * 2);
  unsigned short* nmb = (unsigned short*)alloc((size_t)N_NODES * 128 * 2);
  unsigned short* h1b = (unsigned short*)alloc((size_t)N_NODES * 128 * 2);
  unsigned short* h2b = (unsigned short*)alloc((size_t)N_NODES * 128 * 2);
  unsigned short* wt0 = (unsigned short*)alloc(128 * 256 * 2);
  unsigned short* wt1 = (unsigned short*)alloc(128 * 256 * 2);
  unsigned short* wt2 = (unsigned short*)alloc(64 * 256 * 2);

  hipMemsetAsync(bcount, 0, (size_t)NB * 4, stream);
  k_hist<<<(N_EDGES + 4095) / 4096, 256, 0, stream>>>(dst, bcount);
  k_bscan<<<1, 1024, 0, stream>>>(bcount, boff, bcursor);
  k_scatter<<<(N_EDGES + EPB - 1) / EPB, 256, 0, stream>>>(src, dst, bcursor, stage);
  k_bucket<<<NB, 256, 0, stream>>>(stage, boff, csr, row_off, dinv);

  k_cast<<<(N_NODES * 16 + 255) / 256, 256, 0, stream>>>(x, xb);
  k_wprep<<<64, 256, 0, stream>>>(ws0, wn0, 128, wt0);
  k_wprep<<<64, 256, 0, stream>>>(ws1, wn1, 128, wt1);
  k_wprep<<<32, 256, 0, stream>>>(ws2, wn2, 64, wt2);

  const int GMM = (N_NODES + 63) / 64;  // 1563

  // layer 0
  k_agg<<<25000, 256, 0, stream>>>(xb, row_off, csr, dinv, nmb);
  k_mm<128, true, true><<<GMM, 256, 0, stream>>>(xb, nmb, wt0, b0, h1b);
  // layer 1
  k_agg<<<25000, 256, 0, stream>>>(h1b, row_off, csr, dinv, nmb);
  k_mm<128, true, true><<<GMM, 256, 0, stream>>>(h1b, nmb, wt1, b1, h2b);
  // layer 2
  k_agg<<<25000, 256, 0, stream>>>(h2b, row_off, csr, dinv, nmb);
  k_mm<64, false, false><<<GMM, 256, 0, stream>>>(h2b, nmb, wt2, b2, out);
}

// Round 7
// 264.815 us; speedup vs baseline: 4.9758x; 1.0180x over previous
//
#include <hip/hip_runtime.h>
#include <stdint.h>

#define N_NODES 100000
#define N_EDGES 1000000
#define NB 782  // ceil(N_NODES/128) buckets of 128 nodes

typedef __attribute__((ext_vector_type(2))) _Float16 f16x2;
typedef __attribute__((ext_vector_type(8))) _Float16 f16x8;
typedef __attribute__((ext_vector_type(4))) float f32x4;

__device__ __forceinline__ unsigned short f2h(float f) {
  _Float16 h = (_Float16)f;
  return *(unsigned short*)&h;
}
__device__ __forceinline__ float h2f(unsigned short b) {
  _Float16 h = *(_Float16*)&b;
  return (float)h;
}

// ---------------- bucketed CSR build ----------------

__global__ void k_hist(const int* __restrict__ dst, int* __restrict__ bcount) {
  __shared__ int h[NB];
  int t = threadIdx.x;
  for (int i = t; i < NB; i += 256) h[i] = 0;
  __syncthreads();
  int base = blockIdx.x * 4096;
#pragma unroll
  for (int k = 0; k < 16; k++) {
    int i = base + t + k * 256;
    if (i < N_EDGES) atomicAdd(&h[dst[i] >> 7], 1);
  }
  __syncthreads();
  for (int i = t; i < NB; i += 256)
    if (h[i]) atomicAdd(&bcount[i], h[i]);
}

__global__ __launch_bounds__(1024) void k_bscan(const int* __restrict__ bcount,
                                                int* __restrict__ boff,
                                                int* __restrict__ bcursor) {
  __shared__ int sc[1024];
  int t = threadIdx.x;
  int v = (t < NB) ? bcount[t] : 0;
  sc[t] = v;
  __syncthreads();
  for (int off = 1; off < 1024; off <<= 1) {
    int a = (t >= off) ? sc[t - off] : 0;
    __syncthreads();
    sc[t] += a;
    __syncthreads();
  }
  if (t < NB) {
    boff[t + 1] = sc[t];
    bcursor[t] = sc[t] - v;
  }
  if (t == 0) boff[0] = 0;
}

#define EPB 4096  // edges per scatter block -> 245 workgroups
__global__ void k_scatter(const int* __restrict__ src, const int* __restrict__ dst,
                          int* __restrict__ bcursor, unsigned int* __restrict__ stage) {
  __shared__ int h[NB];
  __shared__ int cur[NB];
  int t = threadIdx.x;
  for (int i = t; i < NB; i += 256) h[i] = 0;
  __syncthreads();
  int base = blockIdx.x * EPB;
#pragma unroll 4
  for (int k = 0; k < EPB / 256; k++) {
    int i = base + t + k * 256;
    if (i < N_EDGES) atomicAdd(&h[dst[i] >> 7], 1);
  }
  __syncthreads();
  for (int i = t; i < NB; i += 256) {
    int c = h[i];
    cur[i] = c ? atomicAdd(&bcursor[i], c) : 0;
  }
  __syncthreads();
#pragma unroll 4
  for (int k = 0; k < EPB / 256; k++) {
    int i = base + t + k * 256;
    if (i < N_EDGES) {
      int d = dst[i];
      int b = d >> 7;
      int pos = atomicAdd(&cur[b], 1);
      stage[pos] = ((unsigned int)(d & 127) << 17) | (unsigned int)src[i];
    }
  }
}

__global__ void k_bucket(const unsigned int* __restrict__ stage, const int* __restrict__ boff,
                         int* __restrict__ csr, int* __restrict__ row_off,
                         float* __restrict__ dinv) {
  __shared__ int cnt[128], sc[128], cur[128];
  int b = blockIdx.x, t = threadIdx.x;
  int e0 = boff[b], e1 = boff[b + 1];
  if (t < 128) cnt[t] = 0;
  __syncthreads();
  for (int e = e0 + t; e < e1; e += 256)
    atomicAdd(&cnt[stage[e] >> 17], 1);
  __syncthreads();
  int myc = (t < 128) ? cnt[t] : 0;
  if (t < 128) sc[t] = myc;
  __syncthreads();
  for (int off = 1; off < 128; off <<= 1) {
    int a = (t < 128 && t >= off) ? sc[t - off] : 0;
    __syncthreads();
    if (t < 128) sc[t] += a;
    __syncthreads();
  }
  if (t < 128) {
    int node = b * 128 + t;
    int ex = sc[t] - myc;
    cur[t] = ex;
    if (node < N_NODES) {
      row_off[node] = e0 + ex;
      dinv[node] = myc ? 1.0f / (float)myc : 0.0f;
    }
  }
  if (b == NB - 1 && t == 0) row_off[N_NODES] = N_EDGES;
  __syncthreads();
  for (int e = e0 + t; e < e1; e += 256) {
    unsigned int v = stage[e];
    int l = v >> 17;
    int pos = e0 + atomicAdd(&cur[l], 1);
    csr[pos] = (int)(v & 0x1FFFFu);
  }
}

// ---------------- fp32 -> f16 cast (x) ----------------
__global__ void k_cast(const float* __restrict__ x, unsigned short* __restrict__ xb) {
  int i = blockIdx.x * 256 + threadIdx.x;
  if (i >= N_NODES * 16) return;
  float4 a = ((const float4*)x)[2 * i];
  float4 b = ((const float4*)x)[2 * i + 1];
  unsigned short r[8] = {f2h(a.x), f2h(a.y), f2h(a.z), f2h(a.w),
                         f2h(b.x), f2h(b.y), f2h(b.z), f2h(b.w)};
  *(uint4*)(xb + (size_t)i * 8) = *(uint4*)r;
}

// ---------------- weight prep: f16, transposed + K-concat ----------------
__global__ void k_wprep(const float* __restrict__ WS, const float* __restrict__ WN,
                        int nout, unsigned short* __restrict__ wt) {
  int t = blockIdx.x * 256 + threadIdx.x;
  if (t >= nout * 128) return;
  int n = t >> 7, k = t & 127;
  wt[n * 256 + k] = f2h(WS[(size_t)k * nout + n]);
  wt[n * 256 + 128 + k] = f2h(WN[(size_t)k * nout + n]);
}

// ---------------- aggregation: wave/node, 16 slots, packed-f16 accumulate ----------------
__global__ void k_agg(const unsigned short* __restrict__ feat,
                      const int* __restrict__ row_off, const int* __restrict__ csr,
                      const float* __restrict__ dinv, unsigned short* __restrict__ nm) {
  int wv = threadIdx.x >> 6, lane = threadIdx.x & 63;
  int node = blockIdx.x * 4 + wv;
  if (node >= N_NODES) return;
  const uint4* fp = (const uint4*)feat;  // 16 uint4 per feature row
  int s0 = row_off[node], s1 = row_off[node + 1];
  int g = lane >> 4, c = lane & 15;
  f16x2 q0 = {0, 0}, q1 = {0, 0}, q2 = {0, 0}, q3 = {0, 0};
  // 4 lane-groups x 4 slots = 16 neighbors per iteration; all index loads
  // issue first, then all feature gathers -> 4 independent chains per lane.
  // accumulate with v_pk_add_f16 (1 inst per uint = per 2 features).
  for (int j = s0 + g; j < s1; j += 16) {
    int i1 = j + 4, i2 = j + 8, i3 = j + 12;
    bool h1 = i1 < s1, h2 = i2 < s1, h3 = i3 < s1;
    int c0 = csr[j];
    int c1 = h1 ? csr[i1] : 0;
    int c2 = h2 ? csr[i2] : 0;
    int c3 = h3 ? csr[i3] : 0;
    uint4 v0, v1, v2, v3;
    v0 = fp[(size_t)c0 * 16 + c];
    if (h1) v1 = fp[(size_t)c1 * 16 + c];
    if (h2) v2 = fp[(size_t)c2 * 16 + c];
    if (h3) v3 = fp[(size_t)c3 * 16 + c];
    q0 += *(const f16x2*)&v0.x; q1 += *(const f16x2*)&v0.y;
    q2 += *(const f16x2*)&v0.z; q3 += *(const f16x2*)&v0.w;
    if (h1) {
      q0 += *(const f16x2*)&v1.x; q1 += *(const f16x2*)&v1.y;
      q2 += *(const f16x2*)&v1.z; q3 += *(const f16x2*)&v1.w;
    }
    if (h2) {
      q0 += *(const f16x2*)&v2.x; q1 += *(const f16x2*)&v2.y;
      q2 += *(const f16x2*)&v2.z; q3 += *(const f16x2*)&v2.w;
    }
    if (h3) {
      q0 += *(const f16x2*)&v3.x; q1 += *(const f16x2*)&v3.y;
      q2 += *(const f16x2*)&v3.z; q3 += *(const f16x2*)&v3.w;
    }
  }
  float a0 = (float)q0[0], a1 = (float)q0[1], a2 = (float)q1[0], a3 = (float)q1[1];
  float a4 = (float)q2[0], a5 = (float)q2[1], a6 = (float)q3[0], a7 = (float)q3[1];
#define RED(x) x += __shfl_xor(x, 16); x += __shfl_xor(x, 32);
  RED(a0) RED(a1) RED(a2) RED(a3) RED(a4) RED(a5) RED(a6) RED(a7)
#undef RED
  if (g == 0) {
    float di = dinv[node];
    uint4 o;
    o.x = ((unsigned int)f2h(a1 * di) << 16) | (unsigned int)f2h(a0 * di);
    o.y = ((unsigned int)f2h(a3 * di) << 16) | (unsigned int)f2h(a2 * di);
    o.z = ((unsigned int)f2h(a5 * di) << 16) | (unsigned int)f2h(a4 * di);
    o.w = ((unsigned int)f2h(a7 * di) << 16) | (unsigned int)f2h(a6 * di);
    ((uint4*)(nm + (size_t)node * 128))[c] = o;
  }
}

// ---------------- MFMA GEMM (f16): OUT = act([A0|A1] @ WT^T + B) ----------------
template <int NOUT, bool RELU, bool OUT_F16>
__global__ __launch_bounds__(256, 4) void k_mm(
    const unsigned short* __restrict__ A0, const unsigned short* __restrict__ A1,
    const unsigned short* __restrict__ WT, const float* __restrict__ Bv,
    void* __restrict__ OUT) {
  constexpr int NFC = NOUT / 64;  // col-frags per wave
  __shared__ __align__(16) unsigned short sm[16896];  // 33792 B
  const int row0 = blockIdx.x * 64;
  const int tid = threadIdx.x;

  for (int i = tid; i < 1024; i += 256) {
    int r = i >> 4, c = i & 15;
    int gr = row0 + r;
    if (gr >= N_NODES) gr = N_NODES - 1;
    *(uint4*)(sm + r * 264 + c * 8) = ((const uint4*)(A0 + (size_t)gr * 128))[c];
    *(uint4*)(sm + r * 264 + 128 + c * 8) = ((const uint4*)(A1 + (size_t)gr * 128))[c];
  }

  const int lane = tid & 63;
  const int w = tid >> 6;
  const int r16 = lane & 15;
  const int kg = lane >> 4;
  const int wc0 = w * (NOUT / 4);

  f32x4 acc[4][NFC];
#pragma unroll
  for (int rf = 0; rf < 4; rf++)
#pragma unroll
    for (int cf = 0; cf < NFC; cf++) acc[rf][cf] = (f32x4){0.f, 0.f, 0.f, 0.f};

  __syncthreads();

  const unsigned short* wtb = WT + (size_t)(wc0 + r16) * 256 + kg * 8;
  const unsigned short* asb = sm + r16 * 264 + kg * 8;

  for (int ks = 0; ks < 8; ks++) {
    f16x8 a[4];
#pragma unroll
    for (int rf = 0; rf < 4; rf++)
      a[rf] = *(const f16x8*)(asb + rf * 16 * 264 + ks * 32);
#pragma unroll
    for (int cf = 0; cf < NFC; cf++) {
      f16x8 b = *(const f16x8*)(wtb + cf * 16 * 256 + ks * 32);
#pragma unroll
      for (int rf = 0; rf < 4; rf++)
        acc[rf][cf] = __builtin_amdgcn_mfma_f32_16x16x32_f16(a[rf], b, acc[rf][cf], 0, 0, 0);
    }
  }

  __syncthreads();  // reuse sm for output staging

  if (OUT_F16) {
    constexpr int LSO = NOUT + 8;
    unsigned short* so = sm;
#pragma unroll
    for (int rf = 0; rf < 4; rf++)
#pragma unroll
      for (int cf = 0; cf < NFC; cf++) {
        int col = wc0 + cf * 16 + r16;
        float bias = Bv[col];
#pragma unroll
        for (int r = 0; r < 4; r++) {
          int row = rf * 16 + kg * 4 + r;
          float v = acc[rf][cf][r] + bias;
          if (RELU) v = fmaxf(v, 0.f);
          so[row * LSO + col] = f2h(v);
        }
      }
    __syncthreads();
    unsigned short* O = (unsigned short*)OUT;
    for (int i = tid; i < 64 * (NOUT / 8); i += 256) {
      int r = i / (NOUT / 8), c = i % (NOUT / 8);
      int gr = row0 + r;
      if (gr < N_NODES)
        *(uint4*)(O + (size_t)gr * NOUT + c * 8) = *(const uint4*)(so + r * LSO + c * 8);
    }
  } else {
    constexpr int LSO = NOUT + 4;
    float* so = (float*)sm;
#pragma unroll
    for (int rf = 0; rf < 4; rf++)
#pragma unroll
      for (int cf = 0; cf < NFC; cf++) {
        int col = wc0 + cf * 16 + r16;
        float bias = Bv[col];
#pragma unroll
        for (int r = 0; r < 4; r++) {
          int row = rf * 16 + kg * 4 + r;
          float v = acc[rf][cf][r] + bias;
          if (RELU) v = fmaxf(v, 0.f);
          so[row * LSO + col] = v;
        }
      }
    __syncthreads();
    float* O = (float*)OUT;
    for (int i = tid; i < 64 * (NOUT / 4); i += 256) {
      int r = i / (NOUT / 4), c = i % (NOUT / 4);
      int gr = row0 + r;
      if (gr < N_NODES)
        *(float4*)(O + (size_t)gr * NOUT + c * 4) = *(const float4*)(so + r * LSO + c * 4);
    }
  }
}

// ---------------- launch ----------------

extern "C" void kernel_launch(void* const* d_in, const int* in_sizes, int n_in,
                              void* d_out, int out_size, void* d_ws, size_t ws_size,
                              hipStream_t stream) {
  const float* x   = (const float*)d_in[0];
  const int*   src = (const int*)d_in[1];
  const int*   dst = (const int*)d_in[2];
  const float* ws0 = (const float*)d_in[3];
  const float* wn0 = (const float*)d_in[4];
  const float* b0  = (const float*)d_in[5];
  const float* ws1 = (const float*)d_in[6];
  const float* wn1 = (const float*)d_in[7];
  const float* b1  = (const float*)d_in[8];
  const float* ws2 = (const float*)d_in[9];
  const float* wn2 = (const float*)d_in[10];
  const float* b2  = (const float*)d_in[11];
  float* out = (float*)d_out;

  uint8_t* base = (uint8_t*)d_ws;
  size_t off = 0;
  auto alloc = [&](size_t bytes) -> void* {
    void* p = base + off;
    off = (off + bytes + 255) & ~(size_t)255;
    return p;
  };
  int*   row_off = (int*)alloc((size_t)(N_NODES + 1) * 4);
  float* dinv    = (float*)alloc((size_t)N_NODES * 4);
  int*   csr     = (int*)alloc((size_t)N_EDGES * 4);
  unsigned int* stage = (unsigned int*)alloc((size_t)N_EDGES * 4);
  int*   bcount  = (int*)alloc((size_t)NB * 4);
  int*   boff    = (int*)alloc((size_t)(NB + 1) * 4);
  int*   bcursor = (int*)alloc((size_t)NB * 4);
  unsigned short* xb  = (unsigned short*)alloc((size_t)N_NODES * 128 * 2);
  unsigned short* nmb = (unsigned short*)alloc((size_t)N_NODES * 128 * 2);
  unsigned short* h1b = (unsigned short*)alloc((size_t)N_NODES * 128 * 2);
  unsigned short* h2b = (unsigned short*)alloc((size_t)N_NODES * 128 * 2);
  unsigned short* wt0 = (unsigned short*)alloc(128 * 256 * 2);
  unsigned short* wt1 = (unsigned short*)alloc(128 * 256 * 2);
  unsigned short* wt2 = (unsigned short*)alloc(64 * 256 * 2);

  hipMemsetAsync(bcount, 0, (size_t)NB * 4, stream);
  k_hist<<<(N_EDGES + 4095) / 4096, 256, 0, stream>>>(dst, bcount);
  k_bscan<<<1, 1024, 0, stream>>>(bcount, boff, bcursor);
  k_scatter<<<(N_EDGES + EPB - 1) / EPB, 256, 0, stream>>>(src, dst, bcursor, stage);
  k_bucket<<<NB, 256, 0, stream>>>(stage, boff, csr, row_off, dinv);

  k_cast<<<(N_NODES * 16 + 255) / 256, 256, 0, stream>>>(x, xb);
  k_wprep<<<64, 256, 0, stream>>>(ws0, wn0, 128, wt0);
  k_wprep<<<64, 256, 0, stream>>>(ws1, wn1, 128, wt1);
  k_wprep<<<32, 256, 0, stream>>>(ws2, wn2, 64, wt2);

  const int GMM = (N_NODES + 63) / 64;  // 1563

  // layer 0
  k_agg<<<25000, 256, 0, stream>>>(xb, row_off, csr, dinv, nmb);
  k_mm<128, true, true><<<GMM, 256, 0, stream>>>(xb, nmb, wt0, b0, h1b);
  // layer 1
  k_agg<<<25000, 256, 0, stream>>>(h1b, row_off, csr, dinv, nmb);
  k_mm<128, true, true><<<GMM, 256, 0, stream>>>(h1b, nmb, wt1, b1, h2b);
  // layer 2
  k_agg<<<25000, 256, 0, stream>>>(h2b, row_off, csr, dinv, nmb);
  k_mm<64, false, false><<<GMM, 256, 0, stream>>>(h2b, nmb, wt2, b2, out);
}